// Round 2
// baseline (2629.312 us; speedup 1.0000x reference)
//
#include <hip/hip_runtime.h>
#include <hip/hip_bf16.h>
#include <cmath>

// Problem constants
#define Bsz 2
#define Lseq 2048
#define Dmod 1024
#define Hhead 16
#define DH 64
#define HID 4096
#define ROWS (Bsz * Lseq)   // 4096
#define TD (3 * Dmod)       // 3072

// ---------------------------------------------------------------------------
// LayerNorm: one block (256 threads) per row of D=1024, float4 vectorized.
// ---------------------------------------------------------------------------
__global__ __launch_bounds__(256) void ln_kernel(const float* __restrict__ x,
                                                 const float* __restrict__ g,
                                                 const float* __restrict__ bta,
                                                 float* __restrict__ out)
{
    int row = blockIdx.x;
    int t = threadIdx.x;                       // 0..255, one float4 each
    const float4* xr = reinterpret_cast<const float4*>(x) + (size_t)row * 256;
    float4 v = xr[t];
    float s  = v.x + v.y + v.z + v.w;
    float s2 = v.x * v.x + v.y * v.y + v.z * v.z + v.w * v.w;
#pragma unroll
    for (int o = 32; o > 0; o >>= 1) {
        s  += __shfl_down(s, o);
        s2 += __shfl_down(s2, o);
    }
    __shared__ float sa[4], sb[4];
    int wv = t >> 6, ln = t & 63;
    if (ln == 0) { sa[wv] = s; sb[wv] = s2; }
    __syncthreads();
    s  = sa[0] + sa[1] + sa[2] + sa[3];
    s2 = sb[0] + sb[1] + sb[2] + sb[3];
    float mean = s * (1.0f / 1024.0f);
    float var  = s2 * (1.0f / 1024.0f) - mean * mean;
    float inv  = rsqrtf(var + 1e-5f);
    float4 gv = reinterpret_cast<const float4*>(g)[t];
    float4 bv = reinterpret_cast<const float4*>(bta)[t];
    float4 o;
    o.x = (v.x - mean) * inv * gv.x + bv.x;
    o.y = (v.y - mean) * inv * gv.y + bv.y;
    o.z = (v.z - mean) * inv * gv.z + bv.z;
    o.w = (v.w - mean) * inv * gv.w + bv.w;
    reinterpret_cast<float4*>(out)[(size_t)row * 256 + t] = o;
}

// ---------------------------------------------------------------------------
// Tiled fp32 GEMM (NT): C[M,N] = act(A[M,K] . W[N,K]^T + bias) (+ res)
// W rows have stride ldw (>= K) so a K-slice of a wider weight can be used.
// 64x64x16 tile, 256 threads, 4x4 per thread. act: 0=none, 1=exact gelu.
// bias may be nullptr.
// ---------------------------------------------------------------------------
__device__ __forceinline__ float gelu_exact(float t)
{
    return 0.5f * t * (1.0f + erff(t * 0.70710678118654752f));
}

__global__ __launch_bounds__(256) void gemm_nt(const float* __restrict__ A,
                                               const float* __restrict__ W,
                                               const float* __restrict__ bias,
                                               const float* __restrict__ res,
                                               float* __restrict__ C,
                                               int M, int N, int K, int ldw, int act)
{
    __shared__ float As[16][65];
    __shared__ float Ws[16][65];
    int tid = threadIdx.x;
    int m0 = blockIdx.y * 64, n0 = blockIdx.x * 64;
    int tx = tid & 15, ty = tid >> 4;          // 16x16 thread grid
    int lr = tid >> 2;                         // 0..63 tile row for loads
    int lq = tid & 3;                          // 0..3  float4 within row
    float acc[4][4] = {};

    for (int k0 = 0; k0 < K; k0 += 16) {
        float4 av = *reinterpret_cast<const float4*>(A + (size_t)(m0 + lr) * K + k0 + lq * 4);
        float4 wv = *reinterpret_cast<const float4*>(W + (size_t)(n0 + lr) * ldw + k0 + lq * 4);
        __syncthreads();   // protect previous iteration's reads
        As[lq * 4 + 0][lr] = av.x; As[lq * 4 + 1][lr] = av.y;
        As[lq * 4 + 2][lr] = av.z; As[lq * 4 + 3][lr] = av.w;
        Ws[lq * 4 + 0][lr] = wv.x; Ws[lq * 4 + 1][lr] = wv.y;
        Ws[lq * 4 + 2][lr] = wv.z; Ws[lq * 4 + 3][lr] = wv.w;
        __syncthreads();
#pragma unroll
        for (int kk = 0; kk < 16; ++kk) {
            float a0 = As[kk][ty * 4 + 0], a1 = As[kk][ty * 4 + 1];
            float a2 = As[kk][ty * 4 + 2], a3 = As[kk][ty * 4 + 3];
            float w0 = Ws[kk][tx * 4 + 0], w1 = Ws[kk][tx * 4 + 1];
            float w2 = Ws[kk][tx * 4 + 2], w3 = Ws[kk][tx * 4 + 3];
            acc[0][0] += a0 * w0; acc[0][1] += a0 * w1; acc[0][2] += a0 * w2; acc[0][3] += a0 * w3;
            acc[1][0] += a1 * w0; acc[1][1] += a1 * w1; acc[1][2] += a1 * w2; acc[1][3] += a1 * w3;
            acc[2][0] += a2 * w0; acc[2][1] += a2 * w1; acc[2][2] += a2 * w2; acc[2][3] += a2 * w3;
            acc[3][0] += a3 * w0; acc[3][1] += a3 * w1; acc[3][2] += a3 * w2; acc[3][3] += a3 * w3;
        }
    }

    float4 bv = make_float4(0.f, 0.f, 0.f, 0.f);
    if (bias) bv = reinterpret_cast<const float4*>(bias)[(n0 >> 2) + tx];
#pragma unroll
    for (int i = 0; i < 4; ++i) {
        int m = m0 + ty * 4 + i;
        float4 o;
        o.x = acc[i][0] + bv.x;
        o.y = acc[i][1] + bv.y;
        o.z = acc[i][2] + bv.z;
        o.w = acc[i][3] + bv.w;
        if (act == 1) {
            o.x = gelu_exact(o.x); o.y = gelu_exact(o.y);
            o.z = gelu_exact(o.z); o.w = gelu_exact(o.w);
        }
        if (res) {
            float4 rv = reinterpret_cast<const float4*>(res + (size_t)m * N)[(n0 >> 2) + tx];
            o.x += rv.x; o.y += rv.y; o.z += rv.z; o.w += rv.w;
        }
        reinterpret_cast<float4*>(C + (size_t)m * N)[(n0 >> 2) + tx] = o;
    }
}

// ---------------------------------------------------------------------------
// Dilated windowed causal attention.
// One wave per query. Keys: j = i, i-2, ..., max(parity(i), i-512)  (<=257).
// qkv layout: [B, L, 3*1024]; q at +0, k at +1024, v at +2048; head h at h*64.
// out layout: [B, L, 1024] (head-concat).
// ---------------------------------------------------------------------------
__global__ __launch_bounds__(256) void attn_kernel(const float* __restrict__ qkv,
                                                   float* __restrict__ out)
{
    __shared__ float sc[4][264];
    __shared__ float qs[4][64];
    int w = threadIdx.x >> 6, lane = threadIdx.x & 63;
    int gw = blockIdx.x * 4 + w;
    int i = gw & (Lseq - 1);
    int h = (gw >> 11) & (Hhead - 1);
    int b = gw >> 15;

    const float* base = qkv + (size_t)b * Lseq * TD;
    const float* qrow = base + (size_t)i * TD + h * 64;
    qs[w][lane] = qrow[lane] * 0.125f;   // 1/sqrt(64)
    __syncthreads();

    int lowj = (i > 512) ? (i - 512) : (i & 1);
    int nk = ((i - lowj) >> 1) + 1;      // <= 257

    // pass 1: scores (each lane handles keys t = lane, lane+64, ...)
    float sv[5];
    int cnt = 0;
    float mx = -1e30f;
    for (int t = lane; t < nk; t += 64) {
        int j = i - 2 * t;
        const float4* krow = reinterpret_cast<const float4*>(base + (size_t)j * TD + 1024 + h * 64);
        float s = 0.0f;
#pragma unroll
        for (int d4 = 0; d4 < 16; ++d4) {
            float4 kk = krow[d4];
            s += qs[w][d4 * 4 + 0] * kk.x + qs[w][d4 * 4 + 1] * kk.y
               + qs[w][d4 * 4 + 2] * kk.z + qs[w][d4 * 4 + 3] * kk.w;
        }
        sv[cnt++] = s;
        mx = fmaxf(mx, s);
    }
#pragma unroll
    for (int o = 32; o > 0; o >>= 1) mx = fmaxf(mx, __shfl_xor(mx, o));

    float lsum = 0.0f;
    cnt = 0;
    for (int t = lane; t < nk; t += 64) {
        float e = __expf(sv[cnt++] - mx);
        sc[w][t] = e;
        lsum += e;
    }
#pragma unroll
    for (int o = 32; o > 0; o >>= 1) lsum += __shfl_xor(lsum, o);
    float inv = 1.0f / lsum;
    __syncthreads();   // make sc[] visible

    // pass 2: out[d=lane] = sum_t p[t] * V[j(t)][lane]   (coalesced V reads)
    float acc = 0.0f;
    for (int t = 0; t < nk; ++t) {
        int j = i - 2 * t;
        acc += sc[w][t] * base[(size_t)j * TD + 2048 + h * 64 + lane];
    }
    out[((size_t)b * Lseq + i) * Dmod + h * 64 + lane] = acc * inv;
}

// ---------------------------------------------------------------------------
// Launch.  Workspace layout (floats), total 16.78M f = 67.1 MB:
//   bufA = d_ws             : qkv (12.58M)  -> ff1 half (8.39M)
//   bufB = d_ws + 12.58M f  : h -> attnout -> h2 (4.19M)   [never overlapped]
// FF is split into two HIDDEN/2 slices so ff1 never outgrows bufA
// (round-1 bug: full ff1 = 16.78M f overflowed into bufB while h2 was
//  still being read by concurrent blocks -> schedule-dependent 0.58 absmax).
// ---------------------------------------------------------------------------
extern "C" void kernel_launch(void* const* d_in, const int* in_sizes, int n_in,
                              void* d_out, int out_size, void* d_ws, size_t ws_size,
                              hipStream_t stream)
{
    const float* x     = (const float*)d_in[0];
    const float* ln1_g = (const float*)d_in[1];
    const float* ln1_b = (const float*)d_in[2];
    const float* w_qkv = (const float*)d_in[3];
    const float* b_qkv = (const float*)d_in[4];
    const float* w_o   = (const float*)d_in[5];
    const float* b_o   = (const float*)d_in[6];
    const float* ln2_g = (const float*)d_in[7];
    const float* ln2_b = (const float*)d_in[8];
    const float* w_ff1 = (const float*)d_in[9];
    const float* b_ff1 = (const float*)d_in[10];
    const float* w_ff2 = (const float*)d_in[11];
    const float* b_ff2 = (const float*)d_in[12];
    float* out = (float*)d_out;

    float* bufA = (float*)d_ws;
    float* bufB = bufA + (size_t)ROWS * TD;
    const int HH = HID / 2;    // 2048

    // 1. h = LN1(x)
    ln_kernel<<<ROWS, 256, 0, stream>>>(x, ln1_g, ln1_b, bufB);
    // 2. qkv = h @ w_qkv^T + b_qkv
    gemm_nt<<<dim3(TD / 64, ROWS / 64), 256, 0, stream>>>(bufB, w_qkv, b_qkv, nullptr,
                                                          bufA, ROWS, TD, Dmod, Dmod, 0);
    // 3. attnout = attention(qkv)
    attn_kernel<<<(Bsz * Hhead * Lseq) / 4, 256, 0, stream>>>(bufA, bufB);
    // 4. out = x + attnout @ w_o^T + b_o
    gemm_nt<<<dim3(Dmod / 64, ROWS / 64), 256, 0, stream>>>(bufB, w_o, b_o, x,
                                                            out, ROWS, Dmod, Dmod, Dmod, 0);
    // 5. h2 = LN2(out)
    ln_kernel<<<ROWS, 256, 0, stream>>>(out, ln2_g, ln2_b, bufB);

    // 6/7 split over HIDDEN halves; ff1 half (4096x2048) lives in bufA.
    // half 0: ff1a = gelu(h2 @ w_ff1[0:2048]^T + b_ff1[0:2048])
    gemm_nt<<<dim3(HH / 64, ROWS / 64), 256, 0, stream>>>(bufB, w_ff1, b_ff1, nullptr,
                                                          bufA, ROWS, HH, Dmod, Dmod, 1);
    //         out = out + ff1a @ w_ff2[:, 0:2048]^T + b_ff2
    gemm_nt<<<dim3(Dmod / 64, ROWS / 64), 256, 0, stream>>>(bufA, w_ff2, b_ff2, out,
                                                            out, ROWS, Dmod, HH, HID, 0);
    // half 1: ff1b = gelu(h2 @ w_ff1[2048:4096]^T + b_ff1[2048:4096])
    gemm_nt<<<dim3(HH / 64, ROWS / 64), 256, 0, stream>>>(bufB, w_ff1 + (size_t)HH * Dmod,
                                                          b_ff1 + HH, nullptr,
                                                          bufA, ROWS, HH, Dmod, Dmod, 1);
    //         out = out + ff1b @ w_ff2[:, 2048:4096]^T   (bias already added)
    gemm_nt<<<dim3(Dmod / 64, ROWS / 64), 256, 0, stream>>>(bufA, w_ff2 + HH, nullptr, out,
                                                            out, ROWS, Dmod, HH, HID, 0);
}

// Round 3
// 783.404 us; speedup vs baseline: 3.3563x; 3.3563x over previous
//
#include <hip/hip_runtime.h>
#include <hip/hip_bf16.h>
#include <cmath>

// Problem constants
#define Bsz 2
#define Lseq 2048
#define Dmod 1024
#define Hhead 16
#define DH 64
#define HID 4096
#define ROWS (Bsz * Lseq)   // 4096
#define TD (3 * Dmod)       // 3072

typedef __attribute__((ext_vector_type(8))) short bf16x8;
typedef __attribute__((ext_vector_type(4))) float f32x4;
typedef unsigned short ushort_t;

typedef const __attribute__((address_space(1))) void gv_t;
typedef __attribute__((address_space(3))) void lv_t;
#define GLDS16(GP, LP) __builtin_amdgcn_global_load_lds((gv_t*)(GP), (lv_t*)(LP), 16, 0, 0)

__device__ __forceinline__ float bf2f(short u)
{
    return __uint_as_float(((unsigned)(unsigned short)u) << 16);
}
__device__ __forceinline__ unsigned pack2(float a, float b)
{
    __hip_bfloat162 t;
    t.x = __float2bfloat16(a);
    t.y = __float2bfloat16(b);
    return *reinterpret_cast<unsigned*>(&t);
}
__device__ __forceinline__ float gelu_exact(float t)
{
    return 0.5f * t * (1.0f + erff(t * 0.70710678118654752f));
}

// ---------------------------------------------------------------------------
// fp32 -> bf16 conversion (weights), float4 loads, uint2 stores.
// ---------------------------------------------------------------------------
__global__ __launch_bounds__(256) void f2b_kernel(const float* __restrict__ in,
                                                  ushort_t* __restrict__ out, int n4)
{
    int i = blockIdx.x * 256 + threadIdx.x;
    if (i >= n4) return;
    float4 v = reinterpret_cast<const float4*>(in)[i];
    uint2 o;
    o.x = pack2(v.x, v.y);
    o.y = pack2(v.z, v.w);
    reinterpret_cast<uint2*>(out)[i] = o;
}

// ---------------------------------------------------------------------------
// LayerNorm: one block per row of D=1024, float4 in, bf16 out.
// ---------------------------------------------------------------------------
__global__ __launch_bounds__(256) void ln_kernel(const float* __restrict__ x,
                                                 const float* __restrict__ g,
                                                 const float* __restrict__ bta,
                                                 ushort_t* __restrict__ out)
{
    int row = blockIdx.x;
    int t = threadIdx.x;
    const float4* xr = reinterpret_cast<const float4*>(x) + (size_t)row * 256;
    float4 v = xr[t];
    float s  = v.x + v.y + v.z + v.w;
    float s2 = v.x * v.x + v.y * v.y + v.z * v.z + v.w * v.w;
#pragma unroll
    for (int o = 32; o > 0; o >>= 1) {
        s  += __shfl_down(s, o);
        s2 += __shfl_down(s2, o);
    }
    __shared__ float sa[4], sb[4];
    int wv = t >> 6, ln = t & 63;
    if (ln == 0) { sa[wv] = s; sb[wv] = s2; }
    __syncthreads();
    s  = sa[0] + sa[1] + sa[2] + sa[3];
    s2 = sb[0] + sb[1] + sb[2] + sb[3];
    float mean = s * (1.0f / 1024.0f);
    float var  = s2 * (1.0f / 1024.0f) - mean * mean;
    float inv  = rsqrtf(var + 1e-5f);
    float4 gv = reinterpret_cast<const float4*>(g)[t];
    float4 bv = reinterpret_cast<const float4*>(bta)[t];
    uint2 o;
    o.x = pack2((v.x - mean) * inv * gv.x + bv.x, (v.y - mean) * inv * gv.y + bv.y);
    o.y = pack2((v.z - mean) * inv * gv.z + bv.z, (v.w - mean) * inv * gv.w + bv.w);
    reinterpret_cast<uint2*>(out)[(size_t)row * 256 + t] = o;
}

// ---------------------------------------------------------------------------
// bf16 MFMA GEMM (NT): C[M,N] = epi(A[M,K] . W[N,K]^T)  (m97 structure)
// 128x128 tile, BK=32, 4 waves, each wave 64x64 = 4x4 frags of 16x16x32.
// A rows stride K; W rows stride ldw. Staging via global_load_lds width 16.
// epi: + bias (fp32, nullable), act(1=gelu), + res (fp32, nullable),
//      out fp32 (obf=0) or bf16 (obf=1).
// ---------------------------------------------------------------------------
__global__ __launch_bounds__(256) void gemm_bt(const ushort_t* __restrict__ A,
                                               const ushort_t* __restrict__ W,
                                               const float* __restrict__ bias,
                                               const float* __restrict__ res,
                                               void* __restrict__ C,
                                               int M, int N, int K, int ldw,
                                               int act, int obf)
{
    __shared__ ushort_t As[128 * 32];
    __shared__ ushort_t Bs[128 * 32];

    int tid = threadIdx.x;
    int w = tid >> 6, lane = tid & 63;
    int m0 = blockIdx.y * 128, n0 = blockIdx.x * 128;
    int wr = (w >> 1) * 64, wc = (w & 1) * 64;

    // staging source: issue q covers tile rows (w*2+q)*16 + lane/4, cols (lane&3)*8
    int srow = (w * 2) * 16 + (lane >> 2);
    int scol = (lane & 3) * 8;
    const ushort_t* ga0 = A + (size_t)(m0 + srow) * K + scol;
    const ushort_t* ga1 = A + (size_t)(m0 + srow + 16) * K + scol;
    const ushort_t* gb0 = W + (size_t)(n0 + srow) * ldw + scol;
    const ushort_t* gb1 = W + (size_t)(n0 + srow + 16) * ldw + scol;
    ushort_t* lA0 = As + (w * 2 + 0) * 512;
    ushort_t* lA1 = As + (w * 2 + 1) * 512;
    ushort_t* lB0 = Bs + (w * 2 + 0) * 512;
    ushort_t* lB1 = Bs + (w * 2 + 1) * 512;

    // fragment read offsets (elements) within [128][32] tile
    int fr = lane & 15;          // row within 16-block
    int fk = (lane >> 4) * 8;    // k offset
    int r0 = (lane >> 4) * 4;    // C/D row base
    int cc = lane & 15;          // C/D col

    f32x4 acc[4][4] = {};

    for (int k0 = 0; k0 < K; k0 += 32) {
        GLDS16(ga0 + k0, lA0);
        GLDS16(ga1 + k0, lA1);
        GLDS16(gb0 + k0, lB0);
        GLDS16(gb1 + k0, lB1);
        __syncthreads();   // drains vmcnt (global_load_lds) + orders LDS

        bf16x8 af[4], bfr[4];
#pragma unroll
        for (int i = 0; i < 4; ++i) {
            af[i]  = *reinterpret_cast<const bf16x8*>(&As[(wr + i * 16 + fr) * 32 + fk]);
            bfr[i] = *reinterpret_cast<const bf16x8*>(&Bs[(wc + i * 16 + fr) * 32 + fk]);
        }
#pragma unroll
        for (int mi = 0; mi < 4; ++mi)
#pragma unroll
            for (int ni = 0; ni < 4; ++ni)
                acc[mi][ni] = __builtin_amdgcn_mfma_f32_16x16x32_bf16(
                    af[mi], bfr[ni], acc[mi][ni], 0, 0, 0);
        __syncthreads();   // protect LDS from next iteration's staging
    }

    // epilogue
    float bv[4];
#pragma unroll
    for (int ni = 0; ni < 4; ++ni)
        bv[ni] = bias ? bias[n0 + wc + ni * 16 + cc] : 0.0f;

#pragma unroll
    for (int mi = 0; mi < 4; ++mi) {
#pragma unroll
        for (int r = 0; r < 4; ++r) {
            int row = m0 + wr + mi * 16 + r0 + r;
            const float* resrow = res ? res + (size_t)row * N : nullptr;
#pragma unroll
            for (int ni = 0; ni < 4; ++ni) {
                int col = n0 + wc + ni * 16 + cc;
                float v = acc[mi][ni][r] + bv[ni];
                if (act == 1) v = gelu_exact(v);
                if (resrow) v += resrow[col];
                if (obf) {
                    reinterpret_cast<ushort_t*>(C)[(size_t)row * N + col] =
                        (ushort_t)(__bfloat16_as_ushort(__float2bfloat16(v)));
                } else {
                    reinterpret_cast<float*>(C)[(size_t)row * N + col] = v;
                }
            }
        }
    }
}

// ---------------------------------------------------------------------------
// Dilated windowed causal attention (bf16 qkv in, bf16 out).
// One wave per query. Keys: j = i, i-2, ..., max(parity(i), i-512) (<=257).
// ---------------------------------------------------------------------------
__global__ __launch_bounds__(256) void attn_kernel(const ushort_t* __restrict__ qkv,
                                                   ushort_t* __restrict__ out)
{
    __shared__ float sc[4][264];
    __shared__ float qs[4][64];
    int w = threadIdx.x >> 6, lane = threadIdx.x & 63;
    int gw = blockIdx.x * 4 + w;
    int i = gw & (Lseq - 1);
    int h = (gw >> 11) & (Hhead - 1);
    int b = gw >> 15;

    const ushort_t* base = qkv + (size_t)b * Lseq * TD;
    qs[w][lane] = bf2f((short)base[(size_t)i * TD + h * 64 + lane]) * 0.125f;
    __syncthreads();

    int lowj = (i > 512) ? (i - 512) : (i & 1);
    int nk = ((i - lowj) >> 1) + 1;      // <= 257

    float sv[5];
    int cnt = 0;
    float mx = -1e30f;
    for (int t = lane; t < nk; t += 64) {
        int j = i - 2 * t;
        const bf16x8* krow = reinterpret_cast<const bf16x8*>(base + (size_t)j * TD + 1024 + h * 64);
        float s = 0.0f;
#pragma unroll
        for (int d8 = 0; d8 < 8; ++d8) {
            bf16x8 kk = krow[d8];
#pragma unroll
            for (int e = 0; e < 8; ++e)
                s += qs[w][d8 * 8 + e] * bf2f(kk[e]);
        }
        sv[cnt++] = s;
        mx = fmaxf(mx, s);
    }
#pragma unroll
    for (int o = 32; o > 0; o >>= 1) mx = fmaxf(mx, __shfl_xor(mx, o));

    float lsum = 0.0f;
    cnt = 0;
    for (int t = lane; t < nk; t += 64) {
        float e = __expf(sv[cnt++] - mx);
        sc[w][t] = e;
        lsum += e;
    }
#pragma unroll
    for (int o = 32; o > 0; o >>= 1) lsum += __shfl_xor(lsum, o);
    float inv = 1.0f / lsum;
    __syncthreads();

    float acc = 0.0f;
    const ushort_t* vp = base + 2048 + h * 64 + lane;
    for (int t = 0; t < nk; ++t) {
        int j = i - 2 * t;
        acc += sc[w][t] * bf2f((short)vp[(size_t)j * TD]);
    }
    out[((size_t)b * Lseq + i) * Dmod + h * 64 + lane] =
        (ushort_t)__bfloat16_as_ushort(__float2bfloat16(acc * inv));
}

// ---------------------------------------------------------------------------
// Launch.  Workspace (bf16 elems), total 33.55M = 67.1 MB (same as round 2):
//   wq 3.15M | wo 1.05M | wf1 4.19M | wf2 4.19M     (bf16 weights, persistent)
//   regA 12.58M : qkv -> ff1_half (8.39M, fits)
//   regB  4.19M : h -> h2
//   regC  4.19M : attnout
// ---------------------------------------------------------------------------
extern "C" void kernel_launch(void* const* d_in, const int* in_sizes, int n_in,
                              void* d_out, int out_size, void* d_ws, size_t ws_size,
                              hipStream_t stream)
{
    const float* x     = (const float*)d_in[0];
    const float* ln1_g = (const float*)d_in[1];
    const float* ln1_b = (const float*)d_in[2];
    const float* w_qkv = (const float*)d_in[3];
    const float* b_qkv = (const float*)d_in[4];
    const float* w_o   = (const float*)d_in[5];
    const float* b_o   = (const float*)d_in[6];
    const float* ln2_g = (const float*)d_in[7];
    const float* ln2_b = (const float*)d_in[8];
    const float* w_ff1 = (const float*)d_in[9];
    const float* b_ff1 = (const float*)d_in[10];
    const float* w_ff2 = (const float*)d_in[11];
    const float* b_ff2 = (const float*)d_in[12];
    float* out = (float*)d_out;

    ushort_t* wq   = (ushort_t*)d_ws;
    ushort_t* wo   = wq  + (size_t)TD * Dmod;
    ushort_t* wf1  = wo  + (size_t)Dmod * Dmod;
    ushort_t* wf2  = wf1 + (size_t)HID * Dmod;
    ushort_t* regA = wf2 + (size_t)Dmod * HID;
    ushort_t* regB = regA + (size_t)ROWS * TD;
    ushort_t* regC = regB + (size_t)ROWS * Dmod;
    const int HH = HID / 2;    // 2048

    // weight conversions (every call; deterministic)
    f2b_kernel<<<(TD * Dmod / 4 + 255) / 256, 256, 0, stream>>>(w_qkv, wq, TD * Dmod / 4);
    f2b_kernel<<<(Dmod * Dmod / 4 + 255) / 256, 256, 0, stream>>>(w_o, wo, Dmod * Dmod / 4);
    f2b_kernel<<<(HID * Dmod / 4 + 255) / 256, 256, 0, stream>>>(w_ff1, wf1, HID * Dmod / 4);
    f2b_kernel<<<(Dmod * HID / 4 + 255) / 256, 256, 0, stream>>>(w_ff2, wf2, Dmod * HID / 4);

    // 1. h = LN1(x)  (bf16)
    ln_kernel<<<ROWS, 256, 0, stream>>>(x, ln1_g, ln1_b, regB);
    // 2. qkv = h @ w_qkv^T + b_qkv  (bf16)
    gemm_bt<<<dim3(TD / 128, ROWS / 128), 256, 0, stream>>>(regB, wq, b_qkv, nullptr,
                                                            regA, ROWS, TD, Dmod, Dmod, 0, 1);
    // 3. attnout = attention(qkv)  (bf16)
    attn_kernel<<<(Bsz * Hhead * Lseq) / 4, 256, 0, stream>>>(regA, regC);
    // 4. out = x + attnout @ w_o^T + b_o  (fp32)
    gemm_bt<<<dim3(Dmod / 128, ROWS / 128), 256, 0, stream>>>(regC, wo, b_o, x,
                                                              out, ROWS, Dmod, Dmod, Dmod, 0, 0);
    // 5. h2 = LN2(out)  (bf16)
    ln_kernel<<<ROWS, 256, 0, stream>>>(out, ln2_g, ln2_b, regB);

    // 6/7 FF split over HIDDEN halves (ff1 half = 4096x2048 bf16 in regA)
    gemm_bt<<<dim3(HH / 128, ROWS / 128), 256, 0, stream>>>(regB, wf1, b_ff1, nullptr,
                                                            regA, ROWS, HH, Dmod, Dmod, 1, 1);
    gemm_bt<<<dim3(Dmod / 128, ROWS / 128), 256, 0, stream>>>(regA, wf2, b_ff2, out,
                                                              out, ROWS, Dmod, HH, HID, 0, 0);
    gemm_bt<<<dim3(HH / 128, ROWS / 128), 256, 0, stream>>>(regB, wf1 + (size_t)HH * Dmod,
                                                            b_ff1 + HH, nullptr,
                                                            regA, ROWS, HH, Dmod, Dmod, 1, 1);
    gemm_bt<<<dim3(Dmod / 128, ROWS / 128), 256, 0, stream>>>(regA, wf2 + HH, nullptr, out,
                                                              out, ROWS, Dmod, HH, HID, 0, 0);
}

// Round 4
// 371.964 us; speedup vs baseline: 7.0687x; 2.1061x over previous
//
#include <hip/hip_runtime.h>
#include <hip/hip_bf16.h>
#include <cmath>

// Problem constants
#define Bsz 2
#define Lseq 2048
#define Dmod 1024
#define Hhead 16
#define DH 64
#define HID 4096
#define ROWS (Bsz * Lseq)   // 4096
#define TD (3 * Dmod)       // 3072

typedef __attribute__((ext_vector_type(8))) short bf16x8;
typedef __attribute__((ext_vector_type(4))) float f32x4;
typedef unsigned short ushort_t;

typedef const __attribute__((address_space(1))) void gv_t;
typedef __attribute__((address_space(3))) void lv_t;
#define GLDS16(GP, LP) __builtin_amdgcn_global_load_lds((gv_t*)(GP), (lv_t*)(LP), 16, 0, 0)

__device__ __forceinline__ float bf2f(short u)
{
    return __uint_as_float(((unsigned)(unsigned short)u) << 16);
}
__device__ __forceinline__ unsigned pack2(float a, float b)
{
    __hip_bfloat162 t;
    t.x = __float2bfloat16(a);
    t.y = __float2bfloat16(b);
    return *reinterpret_cast<unsigned*>(&t);
}
__device__ __forceinline__ float gelu_exact(float t)
{
    return 0.5f * t * (1.0f + erff(t * 0.70710678118654752f));
}

// ---------------------------------------------------------------------------
// fp32 -> bf16 conversion (weights), float4 loads, uint2 stores.
// ---------------------------------------------------------------------------
__global__ __launch_bounds__(256) void f2b_kernel(const float* __restrict__ in,
                                                  ushort_t* __restrict__ out, int n4)
{
    int i = blockIdx.x * 256 + threadIdx.x;
    if (i >= n4) return;
    float4 v = reinterpret_cast<const float4*>(in)[i];
    uint2 o;
    o.x = pack2(v.x, v.y);
    o.y = pack2(v.z, v.w);
    reinterpret_cast<uint2*>(out)[i] = o;
}

// ---------------------------------------------------------------------------
// LayerNorm: one block per row of D=1024, float4 in, bf16 out.
// ---------------------------------------------------------------------------
__global__ __launch_bounds__(256) void ln_kernel(const float* __restrict__ x,
                                                 const float* __restrict__ g,
                                                 const float* __restrict__ bta,
                                                 ushort_t* __restrict__ out)
{
    int row = blockIdx.x;
    int t = threadIdx.x;
    const float4* xr = reinterpret_cast<const float4*>(x) + (size_t)row * 256;
    float4 v = xr[t];
    float s  = v.x + v.y + v.z + v.w;
    float s2 = v.x * v.x + v.y * v.y + v.z * v.z + v.w * v.w;
#pragma unroll
    for (int o = 32; o > 0; o >>= 1) {
        s  += __shfl_down(s, o);
        s2 += __shfl_down(s2, o);
    }
    __shared__ float sa[4], sb[4];
    int wv = t >> 6, ln = t & 63;
    if (ln == 0) { sa[wv] = s; sb[wv] = s2; }
    __syncthreads();
    s  = sa[0] + sa[1] + sa[2] + sa[3];
    s2 = sb[0] + sb[1] + sb[2] + sb[3];
    float mean = s * (1.0f / 1024.0f);
    float var  = s2 * (1.0f / 1024.0f) - mean * mean;
    float inv  = rsqrtf(var + 1e-5f);
    float4 gv = reinterpret_cast<const float4*>(g)[t];
    float4 bv = reinterpret_cast<const float4*>(bta)[t];
    uint2 o;
    o.x = pack2((v.x - mean) * inv * gv.x + bv.x, (v.y - mean) * inv * gv.y + bv.y);
    o.y = pack2((v.z - mean) * inv * gv.z + bv.z, (v.w - mean) * inv * gv.w + bv.w);
    reinterpret_cast<uint2*>(out)[(size_t)row * 256 + t] = o;
}

// ---------------------------------------------------------------------------
// bf16 MFMA GEMM (NT): C[M,N] = epi(A[M,K] . W[N,K]^T)  (m97 structure)
// ---------------------------------------------------------------------------
__global__ __launch_bounds__(256) void gemm_bt(const ushort_t* __restrict__ A,
                                               const ushort_t* __restrict__ W,
                                               const float* __restrict__ bias,
                                               const float* __restrict__ res,
                                               void* __restrict__ C,
                                               int M, int N, int K, int ldw,
                                               int act, int obf)
{
    __shared__ ushort_t As[128 * 32];
    __shared__ ushort_t Bs[128 * 32];

    int tid = threadIdx.x;
    int w = tid >> 6, lane = tid & 63;
    int m0 = blockIdx.y * 128, n0 = blockIdx.x * 128;
    int wr = (w >> 1) * 64, wc = (w & 1) * 64;

    int srow = (w * 2) * 16 + (lane >> 2);
    int scol = (lane & 3) * 8;
    const ushort_t* ga0 = A + (size_t)(m0 + srow) * K + scol;
    const ushort_t* ga1 = A + (size_t)(m0 + srow + 16) * K + scol;
    const ushort_t* gb0 = W + (size_t)(n0 + srow) * ldw + scol;
    const ushort_t* gb1 = W + (size_t)(n0 + srow + 16) * ldw + scol;
    ushort_t* lA0 = As + (w * 2 + 0) * 512;
    ushort_t* lA1 = As + (w * 2 + 1) * 512;
    ushort_t* lB0 = Bs + (w * 2 + 0) * 512;
    ushort_t* lB1 = Bs + (w * 2 + 1) * 512;

    int fr = lane & 15;
    int fk = (lane >> 4) * 8;
    int r0 = (lane >> 4) * 4;
    int cc = lane & 15;

    f32x4 acc[4][4] = {};

    for (int k0 = 0; k0 < K; k0 += 32) {
        GLDS16(ga0 + k0, lA0);
        GLDS16(ga1 + k0, lA1);
        GLDS16(gb0 + k0, lB0);
        GLDS16(gb1 + k0, lB1);
        __syncthreads();

        bf16x8 af[4], bfr[4];
#pragma unroll
        for (int i = 0; i < 4; ++i) {
            af[i]  = *reinterpret_cast<const bf16x8*>(&As[(wr + i * 16 + fr) * 32 + fk]);
            bfr[i] = *reinterpret_cast<const bf16x8*>(&Bs[(wc + i * 16 + fr) * 32 + fk]);
        }
#pragma unroll
        for (int mi = 0; mi < 4; ++mi)
#pragma unroll
            for (int ni = 0; ni < 4; ++ni)
                acc[mi][ni] = __builtin_amdgcn_mfma_f32_16x16x32_bf16(
                    af[mi], bfr[ni], acc[mi][ni], 0, 0, 0);
        __syncthreads();
    }

    float bv[4];
#pragma unroll
    for (int ni = 0; ni < 4; ++ni)
        bv[ni] = bias ? bias[n0 + wc + ni * 16 + cc] : 0.0f;

#pragma unroll
    for (int mi = 0; mi < 4; ++mi) {
#pragma unroll
        for (int r = 0; r < 4; ++r) {
            int row = m0 + wr + mi * 16 + r0 + r;
            const float* resrow = res ? res + (size_t)row * N : nullptr;
#pragma unroll
            for (int ni = 0; ni < 4; ++ni) {
                int col = n0 + wc + ni * 16 + cc;
                float v = acc[mi][ni][r] + bv[ni];
                if (act == 1) v = gelu_exact(v);
                if (resrow) v += resrow[col];
                if (obf) {
                    reinterpret_cast<ushort_t*>(C)[(size_t)row * N + col] =
                        (ushort_t)(__bfloat16_as_ushort(__float2bfloat16(v)));
                } else {
                    reinterpret_cast<float*>(C)[(size_t)row * N + col] = v;
                }
            }
        }
    }
}

// ---------------------------------------------------------------------------
// Flash-style dilated attention via parity compression.
// Parity p subsequence: q' = i>>1 (i = 2q'+p). Mask becomes causal sliding
// window in compressed coords: k' in [q'-256, q'].
// Block = (b, p, h, 64-query tile). 4 waves x 16 queries.
// V staged transposed in LDS once (Vt[64][328], zero-filled OOB).
// Per wave, 10 key-tiles of 32: QK^T (2x2 MFMA 16x16x32, NT), online
// softmax in-register, P -> LDS (bf16), PV (4 MFMA vs Vt, NT).
// ---------------------------------------------------------------------------
__global__ __launch_bounds__(256) void attn_mfma(const ushort_t* __restrict__ qkv,
                                                 ushort_t* __restrict__ out)
{
    __shared__ ushort_t Vt[64][328];      // 41.98 KB; row stride 656 B (16B mult)
    __shared__ ushort_t Pw[4][16][40];    // 5.12 KB; row stride 80 B (16B mult)

    int bid = blockIdx.x;
    int qt = bid & 15, h = (bid >> 4) & 15, p = (bid >> 8) & 1, b = bid >> 9;
    int qt0 = qt * 64;
    int kstart = qt0 - 256;               // 320 staged keys

    const ushort_t* base = qkv + (size_t)b * Lseq * TD;
    int tid = threadIdx.x;

    // ---- stage Vt = V^T for compressed keys [kstart, kstart+320) ----
#pragma unroll
    for (int it = 0; it < 10; ++it) {
        int idx = it * 256 + tid;
        int ko = idx >> 3;                // 0..319
        int dg = idx & 7;                 // 8-dim group
        int kk = kstart + ko;
        bf16x8 v = {};
        if (kk >= 0)
            v = *reinterpret_cast<const bf16x8*>(base + (size_t)(2 * kk + p) * TD + 2048 + h * 64 + dg * 8);
#pragma unroll
        for (int j = 0; j < 8; ++j)
            Vt[dg * 8 + j][ko] = (ushort_t)v[j];
    }

    // ---- Q fragments (A-operand: row = lane&15, k-elems = (lane>>4)*8+j) ----
    int w = tid >> 6, lane = tid & 63;
    int fr = lane & 15, fg = lane >> 4;
    int qw = qt0 + w * 16;
    const ushort_t* qrow = base + (size_t)(2 * (qw + fr) + p) * TD + h * 64;
    bf16x8 qf0 = *reinterpret_cast<const bf16x8*>(qrow + fg * 8);
    bf16x8 qf1 = *reinterpret_cast<const bf16x8*>(qrow + 32 + fg * 8);

    __syncthreads();   // Vt ready

    // online softmax state; reg r holds query qw + fg*4 + r (C/D row layout)
    float m[4]    = {-1e30f, -1e30f, -1e30f, -1e30f};
    float lsum[4] = {};
    f32x4 o[4]    = {};                    // O accs per 16-dim block
    const float scale = 0.125f;            // 1/sqrt(64)
    int qbase = qw + fg * 4;

    for (int t = 0; t < 10; ++t) {
        int kt0 = kstart + t * 32;
        // K fragments (B-operand), rows = keys kt0+fr and kt0+16+fr
        int kk0 = kt0 + fr, kk1 = kk0 + 16;
        int kk0c = kk0 < 0 ? 0 : kk0;
        int kk1c = kk1 < 0 ? 0 : kk1;
        const ushort_t* kr0 = base + (size_t)(2 * kk0c + p) * TD + 1024 + h * 64;
        const ushort_t* kr1 = base + (size_t)(2 * kk1c + p) * TD + 1024 + h * 64;
        bf16x8 k00 = *reinterpret_cast<const bf16x8*>(kr0 + fg * 8);
        bf16x8 k01 = *reinterpret_cast<const bf16x8*>(kr0 + 32 + fg * 8);
        bf16x8 k10 = *reinterpret_cast<const bf16x8*>(kr1 + fg * 8);
        bf16x8 k11 = *reinterpret_cast<const bf16x8*>(kr1 + 32 + fg * 8);

        f32x4 s0 = {}, s1 = {};
        s0 = __builtin_amdgcn_mfma_f32_16x16x32_bf16(qf0, k00, s0, 0, 0, 0);
        s0 = __builtin_amdgcn_mfma_f32_16x16x32_bf16(qf1, k01, s0, 0, 0, 0);
        s1 = __builtin_amdgcn_mfma_f32_16x16x32_bf16(qf0, k10, s1, 0, 0, 0);
        s1 = __builtin_amdgcn_mfma_f32_16x16x32_bf16(qf1, k11, s1, 0, 0, 0);

        // mask + scale; D layout: col fr = key offset, row fg*4+r = query
        int c0 = kt0 + fr, c1 = c0 + 16;
        float v0[4], v1[4], tmax[4];
#pragma unroll
        for (int r = 0; r < 4; ++r) {
            int qq = qbase + r;
            bool a0 = (c0 >= 0) && (c0 <= qq) && (c0 >= qq - 256);
            bool a1 = (c1 >= 0) && (c1 <= qq) && (c1 >= qq - 256);
            v0[r] = a0 ? s0[r] * scale : -1e30f;
            v1[r] = a1 ? s1[r] * scale : -1e30f;
            tmax[r] = fmaxf(v0[r], v1[r]);
        }
        // row-max across the 16-lane col group
#pragma unroll
        for (int off = 1; off < 16; off <<= 1) {
#pragma unroll
            for (int r = 0; r < 4; ++r)
                tmax[r] = fmaxf(tmax[r], __shfl_xor(tmax[r], off));
        }
#pragma unroll
        for (int r = 0; r < 4; ++r) {
            float mn = fmaxf(m[r], tmax[r]);
            float corr = __expf(m[r] - mn);
            m[r] = mn;
            float p0 = __expf(v0[r] - mn);
            float p1 = __expf(v1[r] - mn);
            lsum[r] = lsum[r] * corr + p0 + p1;   // per-lane partial (2 keys)
#pragma unroll
            for (int db = 0; db < 4; ++db)
                o[db][r] *= corr;
            Pw[w][fg * 4 + r][fr]      = (ushort_t)__bfloat16_as_ushort(__float2bfloat16(p0));
            Pw[w][fg * 4 + r][fr + 16] = (ushort_t)__bfloat16_as_ushort(__float2bfloat16(p1));
        }

        // PV: A = P[16q x 32k] (1 frag), B = Vt[d][k] rows (NT)
        bf16x8 pf = *reinterpret_cast<const bf16x8*>(&Pw[w][fr][fg * 8]);
#pragma unroll
        for (int db = 0; db < 4; ++db) {
            bf16x8 vf = *reinterpret_cast<const bf16x8*>(&Vt[db * 16 + fr][t * 32 + fg * 8]);
            o[db] = __builtin_amdgcn_mfma_f32_16x16x32_bf16(pf, vf, o[db], 0, 0, 0);
        }
    }

    // final row-sum of lsum across col group
#pragma unroll
    for (int off = 1; off < 16; off <<= 1) {
#pragma unroll
        for (int r = 0; r < 4; ++r)
            lsum[r] += __shfl_xor(lsum[r], off);
    }
    float inv[4];
#pragma unroll
    for (int r = 0; r < 4; ++r) inv[r] = 1.0f / lsum[r];

    // write out: row i = 2*(qbase+r)+p, col h*64 + db*16 + fr
#pragma unroll
    for (int r = 0; r < 4; ++r) {
        size_t orow = ((size_t)b * Lseq + 2 * (qbase + r) + p) * Dmod + h * 64;
#pragma unroll
        for (int db = 0; db < 4; ++db)
            out[orow + db * 16 + fr] =
                (ushort_t)__bfloat16_as_ushort(__float2bfloat16(o[db][r] * inv[r]));
    }
}

// ---------------------------------------------------------------------------
// Launch.  Workspace (bf16 elems), total 33.55M = 67.1 MB:
//   wq 3.15M | wo 1.05M | wf1 4.19M | wf2 4.19M  (bf16 weights)
//   regA 12.58M : qkv -> ff1_half (8.39M fits)
//   regB  4.19M : h -> h2
//   regC  4.19M : attnout
// ---------------------------------------------------------------------------
extern "C" void kernel_launch(void* const* d_in, const int* in_sizes, int n_in,
                              void* d_out, int out_size, void* d_ws, size_t ws_size,
                              hipStream_t stream)
{
    const float* x     = (const float*)d_in[0];
    const float* ln1_g = (const float*)d_in[1];
    const float* ln1_b = (const float*)d_in[2];
    const float* w_qkv = (const float*)d_in[3];
    const float* b_qkv = (const float*)d_in[4];
    const float* w_o   = (const float*)d_in[5];
    const float* b_o   = (const float*)d_in[6];
    const float* ln2_g = (const float*)d_in[7];
    const float* ln2_b = (const float*)d_in[8];
    const float* w_ff1 = (const float*)d_in[9];
    const float* b_ff1 = (const float*)d_in[10];
    const float* w_ff2 = (const float*)d_in[11];
    const float* b_ff2 = (const float*)d_in[12];
    float* out = (float*)d_out;

    ushort_t* wq   = (ushort_t*)d_ws;
    ushort_t* wo   = wq  + (size_t)TD * Dmod;
    ushort_t* wf1  = wo  + (size_t)Dmod * Dmod;
    ushort_t* wf2  = wf1 + (size_t)HID * Dmod;
    ushort_t* regA = wf2 + (size_t)Dmod * HID;
    ushort_t* regB = regA + (size_t)ROWS * TD;
    ushort_t* regC = regB + (size_t)ROWS * Dmod;
    const int HH = HID / 2;    // 2048

    f2b_kernel<<<(TD * Dmod / 4 + 255) / 256, 256, 0, stream>>>(w_qkv, wq, TD * Dmod / 4);
    f2b_kernel<<<(Dmod * Dmod / 4 + 255) / 256, 256, 0, stream>>>(w_o, wo, Dmod * Dmod / 4);
    f2b_kernel<<<(HID * Dmod / 4 + 255) / 256, 256, 0, stream>>>(w_ff1, wf1, HID * Dmod / 4);
    f2b_kernel<<<(Dmod * HID / 4 + 255) / 256, 256, 0, stream>>>(w_ff2, wf2, Dmod * HID / 4);

    // 1. h = LN1(x)  (bf16)
    ln_kernel<<<ROWS, 256, 0, stream>>>(x, ln1_g, ln1_b, regB);
    // 2. qkv = h @ w_qkv^T + b_qkv  (bf16)
    gemm_bt<<<dim3(TD / 128, ROWS / 128), 256, 0, stream>>>(regB, wq, b_qkv, nullptr,
                                                            regA, ROWS, TD, Dmod, Dmod, 0, 1);
    // 3. attnout = flash dilated attention (bf16)
    attn_mfma<<<Bsz * 2 * Hhead * (1024 / 64), 256, 0, stream>>>(regA, regC);
    // 4. out = x + attnout @ w_o^T + b_o  (fp32)
    gemm_bt<<<dim3(Dmod / 128, ROWS / 128), 256, 0, stream>>>(regC, wo, b_o, x,
                                                              out, ROWS, Dmod, Dmod, Dmod, 0, 0);
    // 5. h2 = LN2(out)  (bf16)
    ln_kernel<<<ROWS, 256, 0, stream>>>(out, ln2_g, ln2_b, regB);

    // 6/7 FF split over HIDDEN halves (ff1 half = 4096x2048 bf16 in regA)
    gemm_bt<<<dim3(HH / 128, ROWS / 128), 256, 0, stream>>>(regB, wf1, b_ff1, nullptr,
                                                            regA, ROWS, HH, Dmod, Dmod, 1, 1);
    gemm_bt<<<dim3(Dmod / 128, ROWS / 128), 256, 0, stream>>>(regA, wf2, b_ff2, out,
                                                              out, ROWS, Dmod, HH, HID, 0, 0);
    gemm_bt<<<dim3(HH / 128, ROWS / 128), 256, 0, stream>>>(regB, wf1 + (size_t)HH * Dmod,
                                                            b_ff1 + HH, nullptr,
                                                            regA, ROWS, HH, Dmod, Dmod, 1, 1);
    gemm_bt<<<dim3(Dmod / 128, ROWS / 128), 256, 0, stream>>>(regA, wf2 + HH, nullptr, out,
                                                              out, ROWS, Dmod, HH, HID, 0, 0);
}

// Round 5
// 309.345 us; speedup vs baseline: 8.4996x; 1.2024x over previous
//
#include <hip/hip_runtime.h>
#include <hip/hip_bf16.h>
#include <cmath>

// Problem constants
#define Bsz 2
#define Lseq 2048
#define Dmod 1024
#define Hhead 16
#define DH 64
#define HID 4096
#define ROWS (Bsz * Lseq)   // 4096
#define TD (3 * Dmod)       // 3072

typedef __attribute__((ext_vector_type(8))) short bf16x8;
typedef __attribute__((ext_vector_type(4))) float f32x4;
typedef unsigned short ushort_t;

typedef const __attribute__((address_space(1))) void gv_t;
typedef __attribute__((address_space(3))) void lv_t;
#define GLDS16(GP, LP) __builtin_amdgcn_global_load_lds((gv_t*)(GP), (lv_t*)(LP), 16, 0, 0)

__device__ __forceinline__ float bf2f(short u)
{
    return __uint_as_float(((unsigned)(unsigned short)u) << 16);
}
__device__ __forceinline__ unsigned pack2(float a, float b)
{
    __hip_bfloat162 t;
    t.x = __float2bfloat16(a);
    t.y = __float2bfloat16(b);
    return *reinterpret_cast<unsigned*>(&t);
}
__device__ __forceinline__ float gelu_exact(float t)
{
    return 0.5f * t * (1.0f + erff(t * 0.70710678118654752f));
}

// ---------------------------------------------------------------------------
// fp32 -> bf16 conversion (weights), float4 loads, uint2 stores.
// ---------------------------------------------------------------------------
__global__ __launch_bounds__(256) void f2b_kernel(const float* __restrict__ in,
                                                  ushort_t* __restrict__ out, int n4)
{
    int i = blockIdx.x * 256 + threadIdx.x;
    if (i >= n4) return;
    float4 v = reinterpret_cast<const float4*>(in)[i];
    uint2 o;
    o.x = pack2(v.x, v.y);
    o.y = pack2(v.z, v.w);
    reinterpret_cast<uint2*>(out)[i] = o;
}

// ---------------------------------------------------------------------------
// LayerNorm: one block per row of D=1024, float4 in, bf16 out.
// ---------------------------------------------------------------------------
__global__ __launch_bounds__(256) void ln_kernel(const float* __restrict__ x,
                                                 const float* __restrict__ g,
                                                 const float* __restrict__ bta,
                                                 ushort_t* __restrict__ out)
{
    int row = blockIdx.x;
    int t = threadIdx.x;
    const float4* xr = reinterpret_cast<const float4*>(x) + (size_t)row * 256;
    float4 v = xr[t];
    float s  = v.x + v.y + v.z + v.w;
    float s2 = v.x * v.x + v.y * v.y + v.z * v.z + v.w * v.w;
#pragma unroll
    for (int o = 32; o > 0; o >>= 1) {
        s  += __shfl_down(s, o);
        s2 += __shfl_down(s2, o);
    }
    __shared__ float sa[4], sb[4];
    int wv = t >> 6, ln = t & 63;
    if (ln == 0) { sa[wv] = s; sb[wv] = s2; }
    __syncthreads();
    s  = sa[0] + sa[1] + sa[2] + sa[3];
    s2 = sb[0] + sb[1] + sb[2] + sb[3];
    float mean = s * (1.0f / 1024.0f);
    float var  = s2 * (1.0f / 1024.0f) - mean * mean;
    float inv  = rsqrtf(var + 1e-5f);
    float4 gv = reinterpret_cast<const float4*>(g)[t];
    float4 bv = reinterpret_cast<const float4*>(bta)[t];
    uint2 o;
    o.x = pack2((v.x - mean) * inv * gv.x + bv.x, (v.y - mean) * inv * gv.y + bv.y);
    o.y = pack2((v.z - mean) * inv * gv.z + bv.z, (v.w - mean) * inv * gv.w + bv.w);
    reinterpret_cast<uint2*>(out)[(size_t)row * 256 + t] = o;
}

// ---------------------------------------------------------------------------
// bf16 MFMA GEMM (NT), 128x128 tile, BK=64 (2 K-slices per barrier pair).
// 4 waves, each 64x64 = 4x4 frags of 16x16x32. Staging via global_load_lds.
// epi: +bias(f32, nullable), act(1=gelu), +res(f32, nullable), out f32/bf16.
// ---------------------------------------------------------------------------
__global__ __launch_bounds__(256) void gemm_bt(const ushort_t* __restrict__ A,
                                               const ushort_t* __restrict__ W,
                                               const float* __restrict__ bias,
                                               const float* __restrict__ res,
                                               void* __restrict__ C,
                                               int M, int N, int K, int ldw,
                                               int act, int obf)
{
    __shared__ ushort_t As[128 * 64];   // 16 KB
    __shared__ ushort_t Bs[128 * 64];   // 16 KB

    int tid = threadIdx.x;
    int w = tid >> 6, lane = tid & 63;
    int m0 = blockIdx.y * 128, n0 = blockIdx.x * 128;
    int wr = (w >> 1) * 64, wc = (w & 1) * 64;

    // staging: each issue = 64 lanes x 16B = 8 rows x 64 cols (1 KB)
    int srow = w * 32 + (lane >> 3);
    int scol = (lane & 7) * 8;
    const ushort_t* ga[4];
    const ushort_t* gb[4];
    ushort_t* la[4];
    ushort_t* lb[4];
#pragma unroll
    for (int q = 0; q < 4; ++q) {
        ga[q] = A + (size_t)(m0 + srow + q * 8) * K + scol;
        gb[q] = W + (size_t)(n0 + srow + q * 8) * ldw + scol;
        la[q] = As + (w * 32 + q * 8) * 64;
        lb[q] = Bs + (w * 32 + q * 8) * 64;
    }

    int fr = lane & 15;
    int fk = (lane >> 4) * 8;
    int r0 = (lane >> 4) * 4;
    int cc = lane & 15;

    f32x4 acc[4][4] = {};

    for (int k0 = 0; k0 < K; k0 += 64) {
#pragma unroll
        for (int q = 0; q < 4; ++q) {
            GLDS16(ga[q] + k0, la[q]);
            GLDS16(gb[q] + k0, lb[q]);
        }
        __syncthreads();   // drains vmcnt + orders LDS

#pragma unroll
        for (int kk = 0; kk < 2; ++kk) {
            bf16x8 af[4], bfr[4];
#pragma unroll
            for (int i = 0; i < 4; ++i) {
                af[i]  = *reinterpret_cast<const bf16x8*>(&As[(wr + i * 16 + fr) * 64 + kk * 32 + fk]);
                bfr[i] = *reinterpret_cast<const bf16x8*>(&Bs[(wc + i * 16 + fr) * 64 + kk * 32 + fk]);
            }
#pragma unroll
            for (int mi = 0; mi < 4; ++mi)
#pragma unroll
                for (int ni = 0; ni < 4; ++ni)
                    acc[mi][ni] = __builtin_amdgcn_mfma_f32_16x16x32_bf16(
                        af[mi], bfr[ni], acc[mi][ni], 0, 0, 0);
        }
        __syncthreads();
    }

    float bv[4];
#pragma unroll
    for (int ni = 0; ni < 4; ++ni)
        bv[ni] = bias ? bias[n0 + wc + ni * 16 + cc] : 0.0f;

#pragma unroll
    for (int mi = 0; mi < 4; ++mi) {
#pragma unroll
        for (int r = 0; r < 4; ++r) {
            int row = m0 + wr + mi * 16 + r0 + r;
            const float* resrow = res ? res + (size_t)row * N : nullptr;
#pragma unroll
            for (int ni = 0; ni < 4; ++ni) {
                int col = n0 + wc + ni * 16 + cc;
                float v = acc[mi][ni][r] + bv[ni];
                if (act == 1) v = gelu_exact(v);
                if (resrow) v += resrow[col];
                if (obf) {
                    reinterpret_cast<ushort_t*>(C)[(size_t)row * N + col] =
                        (ushort_t)__bfloat16_as_ushort(__float2bfloat16(v));
                } else {
                    reinterpret_cast<float*>(C)[(size_t)row * N + col] = v;
                }
            }
        }
    }
}

// ---------------------------------------------------------------------------
// bf16 MFMA GEMM (NT), 128(M) x 64(N) tile, BK=64 — for small-N GEMMs
// (N=1024: grid 16x32=512 blocks -> 2 blocks/CU vs 1 at 128x128).
// 4 waves, each 64x32 = 4x2 frags.
// ---------------------------------------------------------------------------
__global__ __launch_bounds__(256) void gemm_n64(const ushort_t* __restrict__ A,
                                                const ushort_t* __restrict__ W,
                                                const float* __restrict__ bias,
                                                const float* __restrict__ res,
                                                void* __restrict__ C,
                                                int M, int N, int K, int ldw,
                                                int act, int obf)
{
    __shared__ ushort_t As[128 * 64];   // 16 KB
    __shared__ ushort_t Bs[64 * 64];    //  8 KB

    int tid = threadIdx.x;
    int w = tid >> 6, lane = tid & 63;
    int m0 = blockIdx.y * 128, n0 = blockIdx.x * 64;
    int wr = (w >> 1) * 64, wc = (w & 1) * 32;

    int srow = lane >> 3;
    int scol = (lane & 7) * 8;
    const ushort_t* ga[4];
    const ushort_t* gb[2];
    ushort_t* la[4];
    ushort_t* lb[2];
#pragma unroll
    for (int q = 0; q < 4; ++q) {
        ga[q] = A + (size_t)(m0 + w * 32 + q * 8 + srow) * K + scol;
        la[q] = As + (w * 32 + q * 8) * 64;
    }
#pragma unroll
    for (int q = 0; q < 2; ++q) {
        gb[q] = W + (size_t)(n0 + w * 16 + q * 8 + srow) * ldw + scol;
        lb[q] = Bs + (w * 16 + q * 8) * 64;
    }

    int fr = lane & 15;
    int fk = (lane >> 4) * 8;
    int r0 = (lane >> 4) * 4;
    int cc = lane & 15;

    f32x4 acc[4][2] = {};

    for (int k0 = 0; k0 < K; k0 += 64) {
#pragma unroll
        for (int q = 0; q < 4; ++q) GLDS16(ga[q] + k0, la[q]);
#pragma unroll
        for (int q = 0; q < 2; ++q) GLDS16(gb[q] + k0, lb[q]);
        __syncthreads();

#pragma unroll
        for (int kk = 0; kk < 2; ++kk) {
            bf16x8 af[4], bfr[2];
#pragma unroll
            for (int i = 0; i < 4; ++i)
                af[i] = *reinterpret_cast<const bf16x8*>(&As[(wr + i * 16 + fr) * 64 + kk * 32 + fk]);
#pragma unroll
            for (int i = 0; i < 2; ++i)
                bfr[i] = *reinterpret_cast<const bf16x8*>(&Bs[(wc + i * 16 + fr) * 64 + kk * 32 + fk]);
#pragma unroll
            for (int mi = 0; mi < 4; ++mi)
#pragma unroll
                for (int ni = 0; ni < 2; ++ni)
                    acc[mi][ni] = __builtin_amdgcn_mfma_f32_16x16x32_bf16(
                        af[mi], bfr[ni], acc[mi][ni], 0, 0, 0);
        }
        __syncthreads();
    }

    float bv[2];
#pragma unroll
    for (int ni = 0; ni < 2; ++ni)
        bv[ni] = bias ? bias[n0 + wc + ni * 16 + cc] : 0.0f;

#pragma unroll
    for (int mi = 0; mi < 4; ++mi) {
#pragma unroll
        for (int r = 0; r < 4; ++r) {
            int row = m0 + wr + mi * 16 + r0 + r;
            const float* resrow = res ? res + (size_t)row * N : nullptr;
#pragma unroll
            for (int ni = 0; ni < 2; ++ni) {
                int col = n0 + wc + ni * 16 + cc;
                float v = acc[mi][ni][r] + bv[ni];
                if (act == 1) v = gelu_exact(v);
                if (resrow) v += resrow[col];
                if (obf) {
                    reinterpret_cast<ushort_t*>(C)[(size_t)row * N + col] =
                        (ushort_t)__bfloat16_as_ushort(__float2bfloat16(v));
                } else {
                    reinterpret_cast<float*>(C)[(size_t)row * N + col] = v;
                }
            }
        }
    }
}

// ---------------------------------------------------------------------------
// Flash-style dilated attention via parity compression (unchanged, verified).
// ---------------------------------------------------------------------------
__global__ __launch_bounds__(256) void attn_mfma(const ushort_t* __restrict__ qkv,
                                                 ushort_t* __restrict__ out)
{
    __shared__ ushort_t Vt[64][328];
    __shared__ ushort_t Pw[4][16][40];

    int bid = blockIdx.x;
    int qt = bid & 15, h = (bid >> 4) & 15, p = (bid >> 8) & 1, b = bid >> 9;
    int qt0 = qt * 64;
    int kstart = qt0 - 256;

    const ushort_t* base = qkv + (size_t)b * Lseq * TD;
    int tid = threadIdx.x;

#pragma unroll
    for (int it = 0; it < 10; ++it) {
        int idx = it * 256 + tid;
        int ko = idx >> 3;
        int dg = idx & 7;
        int kk = kstart + ko;
        bf16x8 v = {};
        if (kk >= 0)
            v = *reinterpret_cast<const bf16x8*>(base + (size_t)(2 * kk + p) * TD + 2048 + h * 64 + dg * 8);
#pragma unroll
        for (int j = 0; j < 8; ++j)
            Vt[dg * 8 + j][ko] = (ushort_t)v[j];
    }

    int w = tid >> 6, lane = tid & 63;
    int fr = lane & 15, fg = lane >> 4;
    int qw = qt0 + w * 16;
    const ushort_t* qrow = base + (size_t)(2 * (qw + fr) + p) * TD + h * 64;
    bf16x8 qf0 = *reinterpret_cast<const bf16x8*>(qrow + fg * 8);
    bf16x8 qf1 = *reinterpret_cast<const bf16x8*>(qrow + 32 + fg * 8);

    __syncthreads();

    float m[4]    = {-1e30f, -1e30f, -1e30f, -1e30f};
    float lsum[4] = {};
    f32x4 o[4]    = {};
    const float scale = 0.125f;
    int qbase = qw + fg * 4;

    for (int t = 0; t < 10; ++t) {
        int kt0 = kstart + t * 32;
        int kk0 = kt0 + fr, kk1 = kk0 + 16;
        int kk0c = kk0 < 0 ? 0 : kk0;
        int kk1c = kk1 < 0 ? 0 : kk1;
        const ushort_t* kr0 = base + (size_t)(2 * kk0c + p) * TD + 1024 + h * 64;
        const ushort_t* kr1 = base + (size_t)(2 * kk1c + p) * TD + 1024 + h * 64;
        bf16x8 k00 = *reinterpret_cast<const bf16x8*>(kr0 + fg * 8);
        bf16x8 k01 = *reinterpret_cast<const bf16x8*>(kr0 + 32 + fg * 8);
        bf16x8 k10 = *reinterpret_cast<const bf16x8*>(kr1 + fg * 8);
        bf16x8 k11 = *reinterpret_cast<const bf16x8*>(kr1 + 32 + fg * 8);

        f32x4 s0 = {}, s1 = {};
        s0 = __builtin_amdgcn_mfma_f32_16x16x32_bf16(qf0, k00, s0, 0, 0, 0);
        s0 = __builtin_amdgcn_mfma_f32_16x16x32_bf16(qf1, k01, s0, 0, 0, 0);
        s1 = __builtin_amdgcn_mfma_f32_16x16x32_bf16(qf0, k10, s1, 0, 0, 0);
        s1 = __builtin_amdgcn_mfma_f32_16x16x32_bf16(qf1, k11, s1, 0, 0, 0);

        int c0 = kt0 + fr, c1 = c0 + 16;
        float v0[4], v1[4], tmax[4];
#pragma unroll
        for (int r = 0; r < 4; ++r) {
            int qq = qbase + r;
            bool a0 = (c0 >= 0) && (c0 <= qq) && (c0 >= qq - 256);
            bool a1 = (c1 >= 0) && (c1 <= qq) && (c1 >= qq - 256);
            v0[r] = a0 ? s0[r] * scale : -1e30f;
            v1[r] = a1 ? s1[r] * scale : -1e30f;
            tmax[r] = fmaxf(v0[r], v1[r]);
        }
#pragma unroll
        for (int off = 1; off < 16; off <<= 1) {
#pragma unroll
            for (int r = 0; r < 4; ++r)
                tmax[r] = fmaxf(tmax[r], __shfl_xor(tmax[r], off));
        }
#pragma unroll
        for (int r = 0; r < 4; ++r) {
            float mn = fmaxf(m[r], tmax[r]);
            float corr = __expf(m[r] - mn);
            m[r] = mn;
            float p0 = __expf(v0[r] - mn);
            float p1 = __expf(v1[r] - mn);
            lsum[r] = lsum[r] * corr + p0 + p1;
#pragma unroll
            for (int db = 0; db < 4; ++db)
                o[db][r] *= corr;
            Pw[w][fg * 4 + r][fr]      = (ushort_t)__bfloat16_as_ushort(__float2bfloat16(p0));
            Pw[w][fg * 4 + r][fr + 16] = (ushort_t)__bfloat16_as_ushort(__float2bfloat16(p1));
        }

        bf16x8 pf = *reinterpret_cast<const bf16x8*>(&Pw[w][fr][fg * 8]);
#pragma unroll
        for (int db = 0; db < 4; ++db) {
            bf16x8 vf = *reinterpret_cast<const bf16x8*>(&Vt[db * 16 + fr][t * 32 + fg * 8]);
            o[db] = __builtin_amdgcn_mfma_f32_16x16x32_bf16(pf, vf, o[db], 0, 0, 0);
        }
    }

#pragma unroll
    for (int off = 1; off < 16; off <<= 1) {
#pragma unroll
        for (int r = 0; r < 4; ++r)
            lsum[r] += __shfl_xor(lsum[r], off);
    }
    float inv[4];
#pragma unroll
    for (int r = 0; r < 4; ++r) inv[r] = 1.0f / lsum[r];

#pragma unroll
    for (int r = 0; r < 4; ++r) {
        size_t orow = ((size_t)b * Lseq + 2 * (qbase + r) + p) * Dmod + h * 64;
#pragma unroll
        for (int db = 0; db < 4; ++db)
            out[orow + db * 16 + fr] =
                (ushort_t)__bfloat16_as_ushort(__float2bfloat16(o[db][r] * inv[r]));
    }
}

// ---------------------------------------------------------------------------
// Launch.  Workspace (bf16 elems), total 33.554M = 67.1 MB (same as before):
//   wq 3.146M | wo 1.049M | wf1 4.194M | wf2 4.194M   (bf16 weights)
//   bufFF 16.777M : qkv (12.58M) -> ff1 FULL [4096][4096]  (qkv dead by then)
//   bufH   2.097M : h -> h2
//   bufAtt 2.097M : attnout
// ---------------------------------------------------------------------------
extern "C" void kernel_launch(void* const* d_in, const int* in_sizes, int n_in,
                              void* d_out, int out_size, void* d_ws, size_t ws_size,
                              hipStream_t stream)
{
    const float* x     = (const float*)d_in[0];
    const float* ln1_g = (const float*)d_in[1];
    const float* ln1_b = (const float*)d_in[2];
    const float* w_qkv = (const float*)d_in[3];
    const float* b_qkv = (const float*)d_in[4];
    const float* w_o   = (const float*)d_in[5];
    const float* b_o   = (const float*)d_in[6];
    const float* ln2_g = (const float*)d_in[7];
    const float* ln2_b = (const float*)d_in[8];
    const float* w_ff1 = (const float*)d_in[9];
    const float* b_ff1 = (const float*)d_in[10];
    const float* w_ff2 = (const float*)d_in[11];
    const float* b_ff2 = (const float*)d_in[12];
    float* out = (float*)d_out;

    ushort_t* wq     = (ushort_t*)d_ws;
    ushort_t* wo     = wq  + (size_t)TD * Dmod;
    ushort_t* wf1    = wo  + (size_t)Dmod * Dmod;
    ushort_t* wf2    = wf1 + (size_t)HID * Dmod;
    ushort_t* bufFF  = wf2 + (size_t)Dmod * HID;            // 16.777M elems
    ushort_t* bufH   = bufFF + (size_t)ROWS * HID;           // 2.097M
    ushort_t* bufAtt = bufH + (size_t)ROWS * Dmod;           // 2.097M

    f2b_kernel<<<(TD * Dmod / 4 + 255) / 256, 256, 0, stream>>>(w_qkv, wq, TD * Dmod / 4);
    f2b_kernel<<<(Dmod * Dmod / 4 + 255) / 256, 256, 0, stream>>>(w_o, wo, Dmod * Dmod / 4);
    f2b_kernel<<<(HID * Dmod / 4 + 255) / 256, 256, 0, stream>>>(w_ff1, wf1, HID * Dmod / 4);
    f2b_kernel<<<(Dmod * HID / 4 + 255) / 256, 256, 0, stream>>>(w_ff2, wf2, Dmod * HID / 4);

    // 1. h = LN1(x)
    ln_kernel<<<ROWS, 256, 0, stream>>>(x, ln1_g, ln1_b, bufH);
    // 2. qkv = h @ w_qkv^T + b_qkv  (grid 24x32 = 768 blocks)
    gemm_bt<<<dim3(TD / 128, ROWS / 128), 256, 0, stream>>>(bufH, wq, b_qkv, nullptr,
                                                            bufFF, ROWS, TD, Dmod, Dmod, 0, 1);
    // 3. attnout = flash dilated attention
    attn_mfma<<<Bsz * 2 * Hhead * (1024 / 64), 256, 0, stream>>>(bufFF, bufAtt);
    // 4. out = x + attnout @ w_o^T + b_o  (N=1024: 128x64 tile, 512 blocks)
    gemm_n64<<<dim3(Dmod / 64, ROWS / 128), 256, 0, stream>>>(bufAtt, wo, b_o, x,
                                                              out, ROWS, Dmod, Dmod, Dmod, 0, 0);
    // 5. h2 = LN2(out)
    ln_kernel<<<ROWS, 256, 0, stream>>>(out, ln2_g, ln2_b, bufH);
    // 6. ff1 = gelu(h2 @ w_ff1^T + b_ff1)  FULL N=4096 (grid 32x32 = 1024 blocks)
    gemm_bt<<<dim3(HID / 128, ROWS / 128), 256, 0, stream>>>(bufH, wf1, b_ff1, nullptr,
                                                             bufFF, ROWS, HID, Dmod, Dmod, 1, 1);
    // 7. out = out + ff1 @ w_ff2^T + b_ff2  (N=1024, K=4096: 128x64 tile, 512 blocks)
    gemm_n64<<<dim3(Dmod / 64, ROWS / 128), 256, 0, stream>>>(bufFF, wf2, b_ff2, out,
                                                              out, ROWS, Dmod, HID, HID, 0, 0);
}

// Round 6
// 264.539 us; speedup vs baseline: 9.9392x; 1.1694x over previous
//
#include <hip/hip_runtime.h>
#include <hip/hip_bf16.h>
#include <cmath>

// Problem constants
#define Bsz 2
#define Lseq 2048
#define Dmod 1024
#define Hhead 16
#define DH 64
#define HID 4096
#define ROWS (Bsz * Lseq)   // 4096
#define TD (3 * Dmod)       // 3072

typedef __attribute__((ext_vector_type(8))) short bf16x8;
typedef __attribute__((ext_vector_type(4))) float f32x4;
typedef unsigned short ushort_t;

typedef const __attribute__((address_space(1))) void gv_t;
typedef __attribute__((address_space(3))) void lv_t;
#define GLDS16(GP, LP) __builtin_amdgcn_global_load_lds((gv_t*)(GP), (lv_t*)(LP), 16, 0, 0)

__device__ __forceinline__ float bf2f(short u)
{
    return __uint_as_float(((unsigned)(unsigned short)u) << 16);
}
__device__ __forceinline__ unsigned pack2(float a, float b)
{
    __hip_bfloat162 t;
    t.x = __float2bfloat16(a);
    t.y = __float2bfloat16(b);
    return *reinterpret_cast<unsigned*>(&t);
}
__device__ __forceinline__ float gelu_exact(float t)
{
    return 0.5f * t * (1.0f + erff(t * 0.70710678118654752f));
}

// Bijective XCD-aware block remap (T1, m-major within each XCD's chunk).
// Requires gridDim.x*gridDim.y % 8 == 0 (all our grids: 512/768/1024).
__device__ __forceinline__ void xcd_remap(int& mblk, int& nblk)
{
    int nx = gridDim.x;
    int nwg = nx * gridDim.y;
    int id = blockIdx.y * nx + blockIdx.x;
    int cpx = nwg >> 3;
    int swz = (id & 7) * cpx + (id >> 3);
    mblk = swz / nx;
    nblk = swz % nx;
}

// ---------------------------------------------------------------------------
// fp32 -> bf16 conversion (weights), float4 loads, uint2 stores.
// ---------------------------------------------------------------------------
__global__ __launch_bounds__(256) void f2b_kernel(const float* __restrict__ in,
                                                  ushort_t* __restrict__ out, int n4)
{
    int i = blockIdx.x * 256 + threadIdx.x;
    if (i >= n4) return;
    float4 v = reinterpret_cast<const float4*>(in)[i];
    uint2 o;
    o.x = pack2(v.x, v.y);
    o.y = pack2(v.z, v.w);
    reinterpret_cast<uint2*>(out)[i] = o;
}

// ---------------------------------------------------------------------------
// LayerNorm: one block per row of D=1024, float4 in, bf16 out.
// ---------------------------------------------------------------------------
__global__ __launch_bounds__(256) void ln_kernel(const float* __restrict__ x,
                                                 const float* __restrict__ g,
                                                 const float* __restrict__ bta,
                                                 ushort_t* __restrict__ out)
{
    int row = blockIdx.x;
    int t = threadIdx.x;
    const float4* xr = reinterpret_cast<const float4*>(x) + (size_t)row * 256;
    float4 v = xr[t];
    float s  = v.x + v.y + v.z + v.w;
    float s2 = v.x * v.x + v.y * v.y + v.z * v.z + v.w * v.w;
#pragma unroll
    for (int o = 32; o > 0; o >>= 1) {
        s  += __shfl_down(s, o);
        s2 += __shfl_down(s2, o);
    }
    __shared__ float sa[4], sb[4];
    int wv = t >> 6, ln = t & 63;
    if (ln == 0) { sa[wv] = s; sb[wv] = s2; }
    __syncthreads();
    s  = sa[0] + sa[1] + sa[2] + sa[3];
    s2 = sb[0] + sb[1] + sb[2] + sb[3];
    float mean = s * (1.0f / 1024.0f);
    float var  = s2 * (1.0f / 1024.0f) - mean * mean;
    float inv  = rsqrtf(var + 1e-5f);
    float4 gv = reinterpret_cast<const float4*>(g)[t];
    float4 bv = reinterpret_cast<const float4*>(bta)[t];
    uint2 o;
    o.x = pack2((v.x - mean) * inv * gv.x + bv.x, (v.y - mean) * inv * gv.y + bv.y);
    o.y = pack2((v.z - mean) * inv * gv.z + bv.z, (v.w - mean) * inv * gv.w + bv.w);
    reinterpret_cast<uint2*>(out)[(size_t)row * 256 + t] = o;
}

// ---------------------------------------------------------------------------
// bf16 MFMA GEMM (NT), 128x128 tile, BK=64, XOR chunk-swizzled LDS.
// Swizzle (rule #21 both-sides): LDS dest stays linear (global_load_lds
// constraint); global SOURCE chunk is pre-XORed (chunk ^= row&7); fragment
// reads apply the same XOR. 16-way bank conflict -> 2-way (free).
// ---------------------------------------------------------------------------
__global__ __launch_bounds__(256) void gemm_bt(const ushort_t* __restrict__ A,
                                               const ushort_t* __restrict__ W,
                                               const float* __restrict__ bias,
                                               const float* __restrict__ res,
                                               void* __restrict__ C,
                                               int M, int N, int K, int ldw,
                                               int act, int obf)
{
    __shared__ ushort_t As[128 * 64];   // 16 KB
    __shared__ ushort_t Bs[128 * 64];   // 16 KB

    int tid = threadIdx.x;
    int w = tid >> 6, lane = tid & 63;
    int mblk, nblk;
    xcd_remap(mblk, nblk);
    int m0 = mblk * 128, n0 = nblk * 128;
    int wr = (w >> 1) * 64, wc = (w & 1) * 64;

    // staging: each issue = 64 lanes x 16B = 8 rows x 64 cols (1 KB).
    // lane covers row srow = l>>3, LDS slot l&7; source chunk pre-swizzled.
    int srow = lane >> 3;
    int scol = (((lane & 7) ^ (lane >> 3)) & 7) * 8;   // (slot ^ row&7)*8 elems
    const ushort_t* ga[4];
    const ushort_t* gb[4];
    ushort_t* la[4];
    ushort_t* lb[4];
#pragma unroll
    for (int q = 0; q < 4; ++q) {
        ga[q] = A + (size_t)(m0 + w * 32 + q * 8 + srow) * K + scol;
        gb[q] = W + (size_t)(n0 + w * 32 + q * 8 + srow) * ldw + scol;
        la[q] = As + (w * 32 + q * 8) * 64;
        lb[q] = Bs + (w * 32 + q * 8) * 64;
    }

    int fr = lane & 15;
    int fg = lane >> 4;          // k-chunk group 0..3
    int r0 = fg * 4;
    int cc = fr;

    f32x4 acc[4][4] = {};

    for (int k0 = 0; k0 < K; k0 += 64) {
#pragma unroll
        for (int q = 0; q < 4; ++q) {
            GLDS16(ga[q] + k0, la[q]);
            GLDS16(gb[q] + k0, lb[q]);
        }
        __syncthreads();   // drains vmcnt + orders LDS

#pragma unroll
        for (int kk = 0; kk < 2; ++kk) {
            bf16x8 af[4], bfr[4];
#pragma unroll
            for (int i = 0; i < 4; ++i) {
                int ca = ((kk * 4 + fg) ^ (fr & 7)) * 8;   // swizzled chunk
                af[i]  = *reinterpret_cast<const bf16x8*>(&As[(wr + i * 16 + fr) * 64 + ca]);
                bfr[i] = *reinterpret_cast<const bf16x8*>(&Bs[(wc + i * 16 + fr) * 64 + ca]);
            }
#pragma unroll
            for (int mi = 0; mi < 4; ++mi)
#pragma unroll
                for (int ni = 0; ni < 4; ++ni)
                    acc[mi][ni] = __builtin_amdgcn_mfma_f32_16x16x32_bf16(
                        af[mi], bfr[ni], acc[mi][ni], 0, 0, 0);
        }
        __syncthreads();
    }

    float bv[4];
#pragma unroll
    for (int ni = 0; ni < 4; ++ni)
        bv[ni] = bias ? bias[n0 + wc + ni * 16 + cc] : 0.0f;

#pragma unroll
    for (int mi = 0; mi < 4; ++mi) {
#pragma unroll
        for (int r = 0; r < 4; ++r) {
            int row = m0 + wr + mi * 16 + r0 + r;
            const float* resrow = res ? res + (size_t)row * N : nullptr;
#pragma unroll
            for (int ni = 0; ni < 4; ++ni) {
                int col = n0 + wc + ni * 16 + cc;
                float v = acc[mi][ni][r] + bv[ni];
                if (act == 1) v = gelu_exact(v);
                if (resrow) v += resrow[col];
                if (obf) {
                    reinterpret_cast<ushort_t*>(C)[(size_t)row * N + col] =
                        (ushort_t)__bfloat16_as_ushort(__float2bfloat16(v));
                } else {
                    reinterpret_cast<float*>(C)[(size_t)row * N + col] = v;
                }
            }
        }
    }
}

// ---------------------------------------------------------------------------
// bf16 MFMA GEMM (NT), 128(M) x 64(N) tile, BK=64, same swizzle + remap.
// ---------------------------------------------------------------------------
__global__ __launch_bounds__(256) void gemm_n64(const ushort_t* __restrict__ A,
                                                const ushort_t* __restrict__ W,
                                                const float* __restrict__ bias,
                                                const float* __restrict__ res,
                                                void* __restrict__ C,
                                                int M, int N, int K, int ldw,
                                                int act, int obf)
{
    __shared__ ushort_t As[128 * 64];   // 16 KB
    __shared__ ushort_t Bs[64 * 64];    //  8 KB

    int tid = threadIdx.x;
    int w = tid >> 6, lane = tid & 63;
    int mblk, nblk;
    xcd_remap(mblk, nblk);
    int m0 = mblk * 128, n0 = nblk * 64;
    int wr = (w >> 1) * 64, wc = (w & 1) * 32;

    int srow = lane >> 3;
    int scol = (((lane & 7) ^ (lane >> 3)) & 7) * 8;
    const ushort_t* ga[4];
    const ushort_t* gb[2];
    ushort_t* la[4];
    ushort_t* lb[2];
#pragma unroll
    for (int q = 0; q < 4; ++q) {
        ga[q] = A + (size_t)(m0 + w * 32 + q * 8 + srow) * K + scol;
        la[q] = As + (w * 32 + q * 8) * 64;
    }
#pragma unroll
    for (int q = 0; q < 2; ++q) {
        gb[q] = W + (size_t)(n0 + w * 16 + q * 8 + srow) * ldw + scol;
        lb[q] = Bs + (w * 16 + q * 8) * 64;
    }

    int fr = lane & 15;
    int fg = lane >> 4;
    int r0 = fg * 4;
    int cc = fr;

    f32x4 acc[4][2] = {};

    for (int k0 = 0; k0 < K; k0 += 64) {
#pragma unroll
        for (int q = 0; q < 4; ++q) GLDS16(ga[q] + k0, la[q]);
#pragma unroll
        for (int q = 0; q < 2; ++q) GLDS16(gb[q] + k0, lb[q]);
        __syncthreads();

#pragma unroll
        for (int kk = 0; kk < 2; ++kk) {
            bf16x8 af[4], bfr[2];
            int ca = ((kk * 4 + fg) ^ (fr & 7)) * 8;
#pragma unroll
            for (int i = 0; i < 4; ++i)
                af[i] = *reinterpret_cast<const bf16x8*>(&As[(wr + i * 16 + fr) * 64 + ca]);
#pragma unroll
            for (int i = 0; i < 2; ++i)
                bfr[i] = *reinterpret_cast<const bf16x8*>(&Bs[(wc + i * 16 + fr) * 64 + ca]);
#pragma unroll
            for (int mi = 0; mi < 4; ++mi)
#pragma unroll
                for (int ni = 0; ni < 2; ++ni)
                    acc[mi][ni] = __builtin_amdgcn_mfma_f32_16x16x32_bf16(
                        af[mi], bfr[ni], acc[mi][ni], 0, 0, 0);
        }
        __syncthreads();
    }

    float bv[2];
#pragma unroll
    for (int ni = 0; ni < 2; ++ni)
        bv[ni] = bias ? bias[n0 + wc + ni * 16 + cc] : 0.0f;

#pragma unroll
    for (int mi = 0; mi < 4; ++mi) {
#pragma unroll
        for (int r = 0; r < 4; ++r) {
            int row = m0 + wr + mi * 16 + r0 + r;
            const float* resrow = res ? res + (size_t)row * N : nullptr;
#pragma unroll
            for (int ni = 0; ni < 2; ++ni) {
                int col = n0 + wc + ni * 16 + cc;
                float v = acc[mi][ni][r] + bv[ni];
                if (act == 1) v = gelu_exact(v);
                if (resrow) v += resrow[col];
                if (obf) {
                    reinterpret_cast<ushort_t*>(C)[(size_t)row * N + col] =
                        (ushort_t)__bfloat16_as_ushort(__float2bfloat16(v));
                } else {
                    reinterpret_cast<float*>(C)[(size_t)row * N + col] = v;
                }
            }
        }
    }
}

// ---------------------------------------------------------------------------
// Flash-style dilated attention via parity compression (unchanged, verified).
// ---------------------------------------------------------------------------
__global__ __launch_bounds__(256) void attn_mfma(const ushort_t* __restrict__ qkv,
                                                 ushort_t* __restrict__ out)
{
    __shared__ ushort_t Vt[64][328];
    __shared__ ushort_t Pw[4][16][40];

    int bid = blockIdx.x;
    int qt = bid & 15, h = (bid >> 4) & 15, p = (bid >> 8) & 1, b = bid >> 9;
    int qt0 = qt * 64;
    int kstart = qt0 - 256;

    const ushort_t* base = qkv + (size_t)b * Lseq * TD;
    int tid = threadIdx.x;

#pragma unroll
    for (int it = 0; it < 10; ++it) {
        int idx = it * 256 + tid;
        int ko = idx >> 3;
        int dg = idx & 7;
        int kk = kstart + ko;
        bf16x8 v = {};
        if (kk >= 0)
            v = *reinterpret_cast<const bf16x8*>(base + (size_t)(2 * kk + p) * TD + 2048 + h * 64 + dg * 8);
#pragma unroll
        for (int j = 0; j < 8; ++j)
            Vt[dg * 8 + j][ko] = (ushort_t)v[j];
    }

    int w = tid >> 6, lane = tid & 63;
    int fr = lane & 15, fg = lane >> 4;
    int qw = qt0 + w * 16;
    const ushort_t* qrow = base + (size_t)(2 * (qw + fr) + p) * TD + h * 64;
    bf16x8 qf0 = *reinterpret_cast<const bf16x8*>(qrow + fg * 8);
    bf16x8 qf1 = *reinterpret_cast<const bf16x8*>(qrow + 32 + fg * 8);

    __syncthreads();

    float m[4]    = {-1e30f, -1e30f, -1e30f, -1e30f};
    float lsum[4] = {};
    f32x4 o[4]    = {};
    const float scale = 0.125f;
    int qbase = qw + fg * 4;

    for (int t = 0; t < 10; ++t) {
        int kt0 = kstart + t * 32;
        int kk0 = kt0 + fr, kk1 = kk0 + 16;
        int kk0c = kk0 < 0 ? 0 : kk0;
        int kk1c = kk1 < 0 ? 0 : kk1;
        const ushort_t* kr0 = base + (size_t)(2 * kk0c + p) * TD + 1024 + h * 64;
        const ushort_t* kr1 = base + (size_t)(2 * kk1c + p) * TD + 1024 + h * 64;
        bf16x8 k00 = *reinterpret_cast<const bf16x8*>(kr0 + fg * 8);
        bf16x8 k01 = *reinterpret_cast<const bf16x8*>(kr0 + 32 + fg * 8);
        bf16x8 k10 = *reinterpret_cast<const bf16x8*>(kr1 + fg * 8);
        bf16x8 k11 = *reinterpret_cast<const bf16x8*>(kr1 + 32 + fg * 8);

        f32x4 s0 = {}, s1 = {};
        s0 = __builtin_amdgcn_mfma_f32_16x16x32_bf16(qf0, k00, s0, 0, 0, 0);
        s0 = __builtin_amdgcn_mfma_f32_16x16x32_bf16(qf1, k01, s0, 0, 0, 0);
        s1 = __builtin_amdgcn_mfma_f32_16x16x32_bf16(qf0, k10, s1, 0, 0, 0);
        s1 = __builtin_amdgcn_mfma_f32_16x16x32_bf16(qf1, k11, s1, 0, 0, 0);

        int c0 = kt0 + fr, c1 = c0 + 16;
        float v0[4], v1[4], tmax[4];
#pragma unroll
        for (int r = 0; r < 4; ++r) {
            int qq = qbase + r;
            bool a0 = (c0 >= 0) && (c0 <= qq) && (c0 >= qq - 256);
            bool a1 = (c1 >= 0) && (c1 <= qq) && (c1 >= qq - 256);
            v0[r] = a0 ? s0[r] * scale : -1e30f;
            v1[r] = a1 ? s1[r] * scale : -1e30f;
            tmax[r] = fmaxf(v0[r], v1[r]);
        }
#pragma unroll
        for (int off = 1; off < 16; off <<= 1) {
#pragma unroll
            for (int r = 0; r < 4; ++r)
                tmax[r] = fmaxf(tmax[r], __shfl_xor(tmax[r], off));
        }
#pragma unroll
        for (int r = 0; r < 4; ++r) {
            float mn = fmaxf(m[r], tmax[r]);
            float corr = __expf(m[r] - mn);
            m[r] = mn;
            float p0 = __expf(v0[r] - mn);
            float p1 = __expf(v1[r] - mn);
            lsum[r] = lsum[r] * corr + p0 + p1;
#pragma unroll
            for (int db = 0; db < 4; ++db)
                o[db][r] *= corr;
            Pw[w][fg * 4 + r][fr]      = (ushort_t)__bfloat16_as_ushort(__float2bfloat16(p0));
            Pw[w][fg * 4 + r][fr + 16] = (ushort_t)__bfloat16_as_ushort(__float2bfloat16(p1));
        }

        bf16x8 pf = *reinterpret_cast<const bf16x8*>(&Pw[w][fr][fg * 8]);
#pragma unroll
        for (int db = 0; db < 4; ++db) {
            bf16x8 vf = *reinterpret_cast<const bf16x8*>(&Vt[db * 16 + fr][t * 32 + fg * 8]);
            o[db] = __builtin_amdgcn_mfma_f32_16x16x32_bf16(pf, vf, o[db], 0, 0, 0);
        }
    }

#pragma unroll
    for (int off = 1; off < 16; off <<= 1) {
#pragma unroll
        for (int r = 0; r < 4; ++r)
            lsum[r] += __shfl_xor(lsum[r], off);
    }
    float inv[4];
#pragma unroll
    for (int r = 0; r < 4; ++r) inv[r] = 1.0f / lsum[r];

#pragma unroll
    for (int r = 0; r < 4; ++r) {
        size_t orow = ((size_t)b * Lseq + 2 * (qbase + r) + p) * Dmod + h * 64;
#pragma unroll
        for (int db = 0; db < 4; ++db)
            out[orow + db * 16 + fr] =
                (ushort_t)__bfloat16_as_ushort(__float2bfloat16(o[db][r] * inv[r]));
    }
}

// ---------------------------------------------------------------------------
// Launch.  Workspace (bf16 elems), total 33.554M = 67.1 MB:
//   wq 3.146M | wo 1.049M | wf1 4.194M | wf2 4.194M   (bf16 weights)
//   bufFF 16.777M : qkv (12.58M) -> ff1 FULL [4096][4096]  (qkv dead by then)
//   bufH   2.097M : h -> h2
//   bufAtt 2.097M : attnout
// ---------------------------------------------------------------------------
extern "C" void kernel_launch(void* const* d_in, const int* in_sizes, int n_in,
                              void* d_out, int out_size, void* d_ws, size_t ws_size,
                              hipStream_t stream)
{
    const float* x     = (const float*)d_in[0];
    const float* ln1_g = (const float*)d_in[1];
    const float* ln1_b = (const float*)d_in[2];
    const float* w_qkv = (const float*)d_in[3];
    const float* b_qkv = (const float*)d_in[4];
    const float* w_o   = (const float*)d_in[5];
    const float* b_o   = (const float*)d_in[6];
    const float* ln2_g = (const float*)d_in[7];
    const float* ln2_b = (const float*)d_in[8];
    const float* w_ff1 = (const float*)d_in[9];
    const float* b_ff1 = (const float*)d_in[10];
    const float* w_ff2 = (const float*)d_in[11];
    const float* b_ff2 = (const float*)d_in[12];
    float* out = (float*)d_out;

    ushort_t* wq     = (ushort_t*)d_ws;
    ushort_t* wo     = wq  + (size_t)TD * Dmod;
    ushort_t* wf1    = wo  + (size_t)Dmod * Dmod;
    ushort_t* wf2    = wf1 + (size_t)HID * Dmod;
    ushort_t* bufFF  = wf2 + (size_t)Dmod * HID;
    ushort_t* bufH   = bufFF + (size_t)ROWS * HID;
    ushort_t* bufAtt = bufH + (size_t)ROWS * Dmod;

    f2b_kernel<<<(TD * Dmod / 4 + 255) / 256, 256, 0, stream>>>(w_qkv, wq, TD * Dmod / 4);
    f2b_kernel<<<(Dmod * Dmod / 4 + 255) / 256, 256, 0, stream>>>(w_o, wo, Dmod * Dmod / 4);
    f2b_kernel<<<(HID * Dmod / 4 + 255) / 256, 256, 0, stream>>>(w_ff1, wf1, HID * Dmod / 4);
    f2b_kernel<<<(Dmod * HID / 4 + 255) / 256, 256, 0, stream>>>(w_ff2, wf2, Dmod * HID / 4);

    // 1. h = LN1(x)
    ln_kernel<<<ROWS, 256, 0, stream>>>(x, ln1_g, ln1_b, bufH);
    // 2. qkv = h @ w_qkv^T + b_qkv  (grid 24x32 = 768 blocks)
    gemm_bt<<<dim3(TD / 128, ROWS / 128), 256, 0, stream>>>(bufH, wq, b_qkv, nullptr,
                                                            bufFF, ROWS, TD, Dmod, Dmod, 0, 1);
    // 3. attnout = flash dilated attention
    attn_mfma<<<Bsz * 2 * Hhead * (1024 / 64), 256, 0, stream>>>(bufFF, bufAtt);
    // 4. out = x + attnout @ w_o^T + b_o  (N=1024: 128x64 tile, 512 blocks)
    gemm_n64<<<dim3(Dmod / 64, ROWS / 128), 256, 0, stream>>>(bufAtt, wo, b_o, x,
                                                              out, ROWS, Dmod, Dmod, Dmod, 0, 0);
    // 5. h2 = LN2(out)
    ln_kernel<<<ROWS, 256, 0, stream>>>(out, ln2_g, ln2_b, bufH);
    // 6. ff1 = gelu(h2 @ w_ff1^T + b_ff1)  FULL N=4096 (grid 32x32 = 1024 blocks)
    gemm_bt<<<dim3(HID / 128, ROWS / 128), 256, 0, stream>>>(bufH, wf1, b_ff1, nullptr,
                                                             bufFF, ROWS, HID, Dmod, Dmod, 1, 1);
    // 7. out = out + ff1 @ w_ff2^T + b_ff2  (N=1024, K=4096: 128x64 tile, 512 blocks)
    gemm_n64<<<dim3(Dmod / 64, ROWS / 128), 256, 0, stream>>>(bufFF, wf2, b_ff2, out,
                                                              out, ROWS, Dmod, HID, HID, 0, 0);
}

// Round 7
// 246.168 us; speedup vs baseline: 10.6810x; 1.0746x over previous
//
#include <hip/hip_runtime.h>
#include <hip/hip_bf16.h>
#include <cmath>

// Problem constants
#define Bsz 2
#define Lseq 2048
#define Dmod 1024
#define Hhead 16
#define DH 64
#define HID 4096
#define ROWS (Bsz * Lseq)   // 4096
#define TD (3 * Dmod)       // 3072

typedef __attribute__((ext_vector_type(8))) short bf16x8;
typedef __attribute__((ext_vector_type(4))) float f32x4;
typedef unsigned short ushort_t;

typedef const __attribute__((address_space(1))) void gv_t;
typedef __attribute__((address_space(3))) void lv_t;
#define GLDS16(GP, LP) __builtin_amdgcn_global_load_lds((gv_t*)(GP), (lv_t*)(LP), 16, 0, 0)

__device__ __forceinline__ float bf2f(short u)
{
    return __uint_as_float(((unsigned)(unsigned short)u) << 16);
}
__device__ __forceinline__ unsigned pack2(float a, float b)
{
    __hip_bfloat162 t;
    t.x = __float2bfloat16(a);
    t.y = __float2bfloat16(b);
    return *reinterpret_cast<unsigned*>(&t);
}
__device__ __forceinline__ float gelu_exact(float t)
{
    return 0.5f * t * (1.0f + erff(t * 0.70710678118654752f));
}

// Bijective XCD-aware block remap (T1, m-major within each XCD's chunk).
// Requires gridDim.x*gridDim.y % 8 == 0 (all our grids: 512/768/1024).
__device__ __forceinline__ void xcd_remap(int& mblk, int& nblk)
{
    int nx = gridDim.x;
    int nwg = nx * gridDim.y;
    int id = blockIdx.y * nx + blockIdx.x;
    int cpx = nwg >> 3;
    int swz = (id & 7) * cpx + (id >> 3);
    mblk = swz / nx;
    nblk = swz % nx;
}

// ---------------------------------------------------------------------------
// fp32 -> bf16 conversion of all 4 weight tensors in ONE dispatch.
// Segment boundaries are multiples of 256 n4-units so each block is uniform.
// blocks: wq 3072 | wo 1024 | wf1 4096 | wf2 4096  (total 12288)
// ---------------------------------------------------------------------------
__global__ __launch_bounds__(256) void f2b4_kernel(const float* __restrict__ s0, ushort_t* __restrict__ d0,
                                                   const float* __restrict__ s1, ushort_t* __restrict__ d1,
                                                   const float* __restrict__ s2, ushort_t* __restrict__ d2,
                                                   const float* __restrict__ s3, ushort_t* __restrict__ d3)
{
    int blk = blockIdx.x;
    const float* src;
    ushort_t* dst;
    int base;
    if (blk < 3072)      { src = s0; dst = d0; base = blk; }
    else if (blk < 4096) { src = s1; dst = d1; base = blk - 3072; }
    else if (blk < 8192) { src = s2; dst = d2; base = blk - 4096; }
    else                 { src = s3; dst = d3; base = blk - 8192; }
    int i = base * 256 + threadIdx.x;
    float4 v = reinterpret_cast<const float4*>(src)[i];
    uint2 o;
    o.x = pack2(v.x, v.y);
    o.y = pack2(v.z, v.w);
    reinterpret_cast<uint2*>(dst)[i] = o;
}

// ---------------------------------------------------------------------------
// LayerNorm: one block per row of D=1024, float4 in, bf16 out.
// ---------------------------------------------------------------------------
__global__ __launch_bounds__(256) void ln_kernel(const float* __restrict__ x,
                                                 const float* __restrict__ g,
                                                 const float* __restrict__ bta,
                                                 ushort_t* __restrict__ out)
{
    int row = blockIdx.x;
    int t = threadIdx.x;
    const float4* xr = reinterpret_cast<const float4*>(x) + (size_t)row * 256;
    float4 v = xr[t];
    float s  = v.x + v.y + v.z + v.w;
    float s2 = v.x * v.x + v.y * v.y + v.z * v.z + v.w * v.w;
#pragma unroll
    for (int o = 32; o > 0; o >>= 1) {
        s  += __shfl_down(s, o);
        s2 += __shfl_down(s2, o);
    }
    __shared__ float sa[4], sb[4];
    int wv = t >> 6, ln = t & 63;
    if (ln == 0) { sa[wv] = s; sb[wv] = s2; }
    __syncthreads();
    s  = sa[0] + sa[1] + sa[2] + sa[3];
    s2 = sb[0] + sb[1] + sb[2] + sb[3];
    float mean = s * (1.0f / 1024.0f);
    float var  = s2 * (1.0f / 1024.0f) - mean * mean;
    float inv  = rsqrtf(var + 1e-5f);
    float4 gv = reinterpret_cast<const float4*>(g)[t];
    float4 bv = reinterpret_cast<const float4*>(bta)[t];
    uint2 o;
    o.x = pack2((v.x - mean) * inv * gv.x + bv.x, (v.y - mean) * inv * gv.y + bv.y);
    o.y = pack2((v.z - mean) * inv * gv.z + bv.z, (v.w - mean) * inv * gv.w + bv.w);
    reinterpret_cast<uint2*>(out)[(size_t)row * 256 + t] = o;
}

// ---------------------------------------------------------------------------
// bf16 MFMA GEMM (NT), 128x128 tile, BK=64, XOR chunk-swizzled LDS,
// 2-PHASE double-buffered prefetch (T3 minimum recipe):
//   STAGE(buf0); barrier;
//   loop: STAGE(buf1,t+1) ISSUED FIRST; compute(buf0); barrier (vmcnt0 drain);
//         STAGE(buf0,t+2); compute(buf1); barrier; ...
// Buffers are 4 statically named __shared__ arrays so AA proves disjointness
// and the compiler does not insert a defensive vmcnt wait before ds_reads.
// ---------------------------------------------------------------------------
__global__ __launch_bounds__(256) void gemm_bt(const ushort_t* __restrict__ A,
                                               const ushort_t* __restrict__ W,
                                               const float* __restrict__ bias,
                                               const float* __restrict__ res,
                                               void* __restrict__ C,
                                               int M, int N, int K, int ldw,
                                               int act, int obf)
{
    __shared__ ushort_t As0[128 * 64];   // 16 KB each, 64 KB total
    __shared__ ushort_t Bs0[128 * 64];
    __shared__ ushort_t As1[128 * 64];
    __shared__ ushort_t Bs1[128 * 64];

    int tid = threadIdx.x;
    int w = tid >> 6, lane = tid & 63;
    int mblk, nblk;
    xcd_remap(mblk, nblk);
    int m0 = mblk * 128, n0 = nblk * 128;
    int wr = (w >> 1) * 64, wc = (w & 1) * 64;

    // staging: each issue = 64 lanes x 16B = 8 rows x 64 cols (1 KB).
    int srow = lane >> 3;
    int scol = (((lane & 7) ^ (lane >> 3)) & 7) * 8;   // pre-swizzled source chunk
    const ushort_t* ga[4];
    const ushort_t* gb[4];
    int lofs[4];
#pragma unroll
    for (int q = 0; q < 4; ++q) {
        ga[q] = A + (size_t)(m0 + w * 32 + q * 8 + srow) * K + scol;
        gb[q] = W + (size_t)(n0 + w * 32 + q * 8 + srow) * ldw + scol;
        lofs[q] = (w * 32 + q * 8) * 64;
    }

    int fr = lane & 15;
    int fg = lane >> 4;          // k-chunk group 0..3
    int r0 = fg * 4;
    int cc = fr;

    f32x4 acc[4][4] = {};

    auto stage = [&](ushort_t* AS, ushort_t* BS, int k0) {
#pragma unroll
        for (int q = 0; q < 4; ++q) {
            GLDS16(ga[q] + k0, AS + lofs[q]);
            GLDS16(gb[q] + k0, BS + lofs[q]);
        }
    };
    auto compute = [&](const ushort_t* AS, const ushort_t* BS) {
#pragma unroll
        for (int kk = 0; kk < 2; ++kk) {
            bf16x8 af[4], bfr[4];
            int ca = ((kk * 4 + fg) ^ (fr & 7)) * 8;   // swizzled chunk
#pragma unroll
            for (int i = 0; i < 4; ++i) {
                af[i]  = *reinterpret_cast<const bf16x8*>(&AS[(wr + i * 16 + fr) * 64 + ca]);
                bfr[i] = *reinterpret_cast<const bf16x8*>(&BS[(wc + i * 16 + fr) * 64 + ca]);
            }
#pragma unroll
            for (int mi = 0; mi < 4; ++mi)
#pragma unroll
                for (int ni = 0; ni < 4; ++ni)
                    acc[mi][ni] = __builtin_amdgcn_mfma_f32_16x16x32_bf16(
                        af[mi], bfr[ni], acc[mi][ni], 0, 0, 0);
        }
    };

    int nt = K >> 6;    // K-tiles of 64; even for all our shapes (16 or 64)
    stage(As0, Bs0, 0);
    __syncthreads();
    for (int t = 0; t < nt; t += 2) {
        stage(As1, Bs1, (t + 1) * 64);   // in flight during compute of buf0
        compute(As0, Bs0);
        __syncthreads();                 // drains vmcnt(0): buf1 ready; buf0 free
        if (t + 2 < nt) stage(As0, Bs0, (t + 2) * 64);
        compute(As1, Bs1);
        __syncthreads();
    }

    float bv[4];
#pragma unroll
    for (int ni = 0; ni < 4; ++ni)
        bv[ni] = bias ? bias[n0 + wc + ni * 16 + cc] : 0.0f;

#pragma unroll
    for (int mi = 0; mi < 4; ++mi) {
#pragma unroll
        for (int r = 0; r < 4; ++r) {
            int row = m0 + wr + mi * 16 + r0 + r;
            const float* resrow = res ? res + (size_t)row * N : nullptr;
#pragma unroll
            for (int ni = 0; ni < 4; ++ni) {
                int col = n0 + wc + ni * 16 + cc;
                float v = acc[mi][ni][r] + bv[ni];
                if (act == 1) v = gelu_exact(v);
                if (resrow) v += resrow[col];
                if (obf) {
                    reinterpret_cast<ushort_t*>(C)[(size_t)row * N + col] =
                        (ushort_t)__bfloat16_as_ushort(__float2bfloat16(v));
                } else {
                    reinterpret_cast<float*>(C)[(size_t)row * N + col] = v;
                }
            }
        }
    }
}

// ---------------------------------------------------------------------------
// bf16 MFMA GEMM (NT), 128(M) x 64(N) tile, BK=64, swizzle + remap,
// same 2-phase double-buffered prefetch. LDS 48 KB -> 3 blocks/CU.
// ---------------------------------------------------------------------------
__global__ __launch_bounds__(256) void gemm_n64(const ushort_t* __restrict__ A,
                                                const ushort_t* __restrict__ W,
                                                const float* __restrict__ bias,
                                                const float* __restrict__ res,
                                                void* __restrict__ C,
                                                int M, int N, int K, int ldw,
                                                int act, int obf)
{
    __shared__ ushort_t As0[128 * 64];   // 16 KB
    __shared__ ushort_t Bs0[64 * 64];    //  8 KB
    __shared__ ushort_t As1[128 * 64];
    __shared__ ushort_t Bs1[64 * 64];

    int tid = threadIdx.x;
    int w = tid >> 6, lane = tid & 63;
    int mblk, nblk;
    xcd_remap(mblk, nblk);
    int m0 = mblk * 128, n0 = nblk * 64;
    int wr = (w >> 1) * 64, wc = (w & 1) * 32;

    int srow = lane >> 3;
    int scol = (((lane & 7) ^ (lane >> 3)) & 7) * 8;
    const ushort_t* ga[4];
    const ushort_t* gb[2];
    int laofs[4], lbofs[2];
#pragma unroll
    for (int q = 0; q < 4; ++q) {
        ga[q] = A + (size_t)(m0 + w * 32 + q * 8 + srow) * K + scol;
        laofs[q] = (w * 32 + q * 8) * 64;
    }
#pragma unroll
    for (int q = 0; q < 2; ++q) {
        gb[q] = W + (size_t)(n0 + w * 16 + q * 8 + srow) * ldw + scol;
        lbofs[q] = (w * 16 + q * 8) * 64;
    }

    int fr = lane & 15;
    int fg = lane >> 4;
    int r0 = fg * 4;
    int cc = fr;

    f32x4 acc[4][2] = {};

    auto stage = [&](ushort_t* AS, ushort_t* BS, int k0) {
#pragma unroll
        for (int q = 0; q < 4; ++q) GLDS16(ga[q] + k0, AS + laofs[q]);
#pragma unroll
        for (int q = 0; q < 2; ++q) GLDS16(gb[q] + k0, BS + lbofs[q]);
    };
    auto compute = [&](const ushort_t* AS, const ushort_t* BS) {
#pragma unroll
        for (int kk = 0; kk < 2; ++kk) {
            bf16x8 af[4], bfr[2];
            int ca = ((kk * 4 + fg) ^ (fr & 7)) * 8;
#pragma unroll
            for (int i = 0; i < 4; ++i)
                af[i] = *reinterpret_cast<const bf16x8*>(&AS[(wr + i * 16 + fr) * 64 + ca]);
#pragma unroll
            for (int i = 0; i < 2; ++i)
                bfr[i] = *reinterpret_cast<const bf16x8*>(&BS[(wc + i * 16 + fr) * 64 + ca]);
#pragma unroll
            for (int mi = 0; mi < 4; ++mi)
#pragma unroll
                for (int ni = 0; ni < 2; ++ni)
                    acc[mi][ni] = __builtin_amdgcn_mfma_f32_16x16x32_bf16(
                        af[mi], bfr[ni], acc[mi][ni], 0, 0, 0);
        }
    };

    int nt = K >> 6;
    stage(As0, Bs0, 0);
    __syncthreads();
    for (int t = 0; t < nt; t += 2) {
        stage(As1, Bs1, (t + 1) * 64);
        compute(As0, Bs0);
        __syncthreads();
        if (t + 2 < nt) stage(As0, Bs0, (t + 2) * 64);
        compute(As1, Bs1);
        __syncthreads();
    }

    float bv[2];
#pragma unroll
    for (int ni = 0; ni < 2; ++ni)
        bv[ni] = bias ? bias[n0 + wc + ni * 16 + cc] : 0.0f;

#pragma unroll
    for (int mi = 0; mi < 4; ++mi) {
#pragma unroll
        for (int r = 0; r < 4; ++r) {
            int row = m0 + wr + mi * 16 + r0 + r;
            const float* resrow = res ? res + (size_t)row * N : nullptr;
#pragma unroll
            for (int ni = 0; ni < 2; ++ni) {
                int col = n0 + wc + ni * 16 + cc;
                float v = acc[mi][ni][r] + bv[ni];
                if (act == 1) v = gelu_exact(v);
                if (resrow) v += resrow[col];
                if (obf) {
                    reinterpret_cast<ushort_t*>(C)[(size_t)row * N + col] =
                        (ushort_t)__bfloat16_as_ushort(__float2bfloat16(v));
                } else {
                    reinterpret_cast<float*>(C)[(size_t)row * N + col] = v;
                }
            }
        }
    }
}

// ---------------------------------------------------------------------------
// Flash-style dilated attention via parity compression (unchanged, verified).
// ---------------------------------------------------------------------------
__global__ __launch_bounds__(256) void attn_mfma(const ushort_t* __restrict__ qkv,
                                                 ushort_t* __restrict__ out)
{
    __shared__ ushort_t Vt[64][328];
    __shared__ ushort_t Pw[4][16][40];

    int bid = blockIdx.x;
    int qt = bid & 15, h = (bid >> 4) & 15, p = (bid >> 8) & 1, b = bid >> 9;
    int qt0 = qt * 64;
    int kstart = qt0 - 256;

    const ushort_t* base = qkv + (size_t)b * Lseq * TD;
    int tid = threadIdx.x;

#pragma unroll
    for (int it = 0; it < 10; ++it) {
        int idx = it * 256 + tid;
        int ko = idx >> 3;
        int dg = idx & 7;
        int kk = kstart + ko;
        bf16x8 v = {};
        if (kk >= 0)
            v = *reinterpret_cast<const bf16x8*>(base + (size_t)(2 * kk + p) * TD + 2048 + h * 64 + dg * 8);
#pragma unroll
        for (int j = 0; j < 8; ++j)
            Vt[dg * 8 + j][ko] = (ushort_t)v[j];
    }

    int w = tid >> 6, lane = tid & 63;
    int fr = lane & 15, fg = lane >> 4;
    int qw = qt0 + w * 16;
    const ushort_t* qrow = base + (size_t)(2 * (qw + fr) + p) * TD + h * 64;
    bf16x8 qf0 = *reinterpret_cast<const bf16x8*>(qrow + fg * 8);
    bf16x8 qf1 = *reinterpret_cast<const bf16x8*>(qrow + 32 + fg * 8);

    __syncthreads();

    float m[4]    = {-1e30f, -1e30f, -1e30f, -1e30f};
    float lsum[4] = {};
    f32x4 o[4]    = {};
    const float scale = 0.125f;
    int qbase = qw + fg * 4;

    for (int t = 0; t < 10; ++t) {
        int kt0 = kstart + t * 32;
        int kk0 = kt0 + fr, kk1 = kk0 + 16;
        int kk0c = kk0 < 0 ? 0 : kk0;
        int kk1c = kk1 < 0 ? 0 : kk1;
        const ushort_t* kr0 = base + (size_t)(2 * kk0c + p) * TD + 1024 + h * 64;
        const ushort_t* kr1 = base + (size_t)(2 * kk1c + p) * TD + 1024 + h * 64;
        bf16x8 k00 = *reinterpret_cast<const bf16x8*>(kr0 + fg * 8);
        bf16x8 k01 = *reinterpret_cast<const bf16x8*>(kr0 + 32 + fg * 8);
        bf16x8 k10 = *reinterpret_cast<const bf16x8*>(kr1 + fg * 8);
        bf16x8 k11 = *reinterpret_cast<const bf16x8*>(kr1 + 32 + fg * 8);

        f32x4 s0 = {}, s1 = {};
        s0 = __builtin_amdgcn_mfma_f32_16x16x32_bf16(qf0, k00, s0, 0, 0, 0);
        s0 = __builtin_amdgcn_mfma_f32_16x16x32_bf16(qf1, k01, s0, 0, 0, 0);
        s1 = __builtin_amdgcn_mfma_f32_16x16x32_bf16(qf0, k10, s1, 0, 0, 0);
        s1 = __builtin_amdgcn_mfma_f32_16x16x32_bf16(qf1, k11, s1, 0, 0, 0);

        int c0 = kt0 + fr, c1 = c0 + 16;
        float v0[4], v1[4], tmax[4];
#pragma unroll
        for (int r = 0; r < 4; ++r) {
            int qq = qbase + r;
            bool a0 = (c0 >= 0) && (c0 <= qq) && (c0 >= qq - 256);
            bool a1 = (c1 >= 0) && (c1 <= qq) && (c1 >= qq - 256);
            v0[r] = a0 ? s0[r] * scale : -1e30f;
            v1[r] = a1 ? s1[r] * scale : -1e30f;
            tmax[r] = fmaxf(v0[r], v1[r]);
        }
#pragma unroll
        for (int off = 1; off < 16; off <<= 1) {
#pragma unroll
            for (int r = 0; r < 4; ++r)
                tmax[r] = fmaxf(tmax[r], __shfl_xor(tmax[r], off));
        }
#pragma unroll
        for (int r = 0; r < 4; ++r) {
            float mn = fmaxf(m[r], tmax[r]);
            float corr = __expf(m[r] - mn);
            m[r] = mn;
            float p0 = __expf(v0[r] - mn);
            float p1 = __expf(v1[r] - mn);
            lsum[r] = lsum[r] * corr + p0 + p1;
#pragma unroll
            for (int db = 0; db < 4; ++db)
                o[db][r] *= corr;
            Pw[w][fg * 4 + r][fr]      = (ushort_t)__bfloat16_as_ushort(__float2bfloat16(p0));
            Pw[w][fg * 4 + r][fr + 16] = (ushort_t)__bfloat16_as_ushort(__float2bfloat16(p1));
        }

        bf16x8 pf = *reinterpret_cast<const bf16x8*>(&Pw[w][fr][fg * 8]);
#pragma unroll
        for (int db = 0; db < 4; ++db) {
            bf16x8 vf = *reinterpret_cast<const bf16x8*>(&Vt[db * 16 + fr][t * 32 + fg * 8]);
            o[db] = __builtin_amdgcn_mfma_f32_16x16x32_bf16(pf, vf, o[db], 0, 0, 0);
        }
    }

#pragma unroll
    for (int off = 1; off < 16; off <<= 1) {
#pragma unroll
        for (int r = 0; r < 4; ++r)
            lsum[r] += __shfl_xor(lsum[r], off);
    }
    float inv[4];
#pragma unroll
    for (int r = 0; r < 4; ++r) inv[r] = 1.0f / lsum[r];

#pragma unroll
    for (int r = 0; r < 4; ++r) {
        size_t orow = ((size_t)b * Lseq + 2 * (qbase + r) + p) * Dmod + h * 64;
#pragma unroll
        for (int db = 0; db < 4; ++db)
            out[orow + db * 16 + fr] =
                (ushort_t)__bfloat16_as_ushort(__float2bfloat16(o[db][r] * inv[r]));
    }
}

// ---------------------------------------------------------------------------
// Launch.  Workspace (bf16 elems), total 33.554M = 67.1 MB:
//   wq 3.146M | wo 1.049M | wf1 4.194M | wf2 4.194M   (bf16 weights)
//   bufFF 16.777M : qkv (12.58M) -> ff1 FULL [4096][4096]  (qkv dead by then)
//   bufH   2.097M : h -> h2
//   bufAtt 2.097M : attnout
// ---------------------------------------------------------------------------
extern "C" void kernel_launch(void* const* d_in, const int* in_sizes, int n_in,
                              void* d_out, int out_size, void* d_ws, size_t ws_size,
                              hipStream_t stream)
{
    const float* x     = (const float*)d_in[0];
    const float* ln1_g = (const float*)d_in[1];
    const float* ln1_b = (const float*)d_in[2];
    const float* w_qkv = (const float*)d_in[3];
    const float* b_qkv = (const float*)d_in[4];
    const float* w_o   = (const float*)d_in[5];
    const float* b_o   = (const float*)d_in[6];
    const float* ln2_g = (const float*)d_in[7];
    const float* ln2_b = (const float*)d_in[8];
    const float* w_ff1 = (const float*)d_in[9];
    const float* b_ff1 = (const float*)d_in[10];
    const float* w_ff2 = (const float*)d_in[11];
    const float* b_ff2 = (const float*)d_in[12];
    float* out = (float*)d_out;

    ushort_t* wq     = (ushort_t*)d_ws;
    ushort_t* wo     = wq  + (size_t)TD * Dmod;
    ushort_t* wf1    = wo  + (size_t)Dmod * Dmod;
    ushort_t* wf2    = wf1 + (size_t)HID * Dmod;
    ushort_t* bufFF  = wf2 + (size_t)Dmod * HID;
    ushort_t* bufH   = bufFF + (size_t)ROWS * HID;
    ushort_t* bufAtt = bufH + (size_t)ROWS * Dmod;

    // all weight conversions in one dispatch
    f2b4_kernel<<<12288, 256, 0, stream>>>(w_qkv, wq, w_o, wo, w_ff1, wf1, w_ff2, wf2);

    // 1. h = LN1(x)
    ln_kernel<<<ROWS, 256, 0, stream>>>(x, ln1_g, ln1_b, bufH);
    // 2. qkv = h @ w_qkv^T + b_qkv  (grid 24x32 = 768 blocks)
    gemm_bt<<<dim3(TD / 128, ROWS / 128), 256, 0, stream>>>(bufH, wq, b_qkv, nullptr,
                                                            bufFF, ROWS, TD, Dmod, Dmod, 0, 1);
    // 3. attnout = flash dilated attention
    attn_mfma<<<Bsz * 2 * Hhead * (1024 / 64), 256, 0, stream>>>(bufFF, bufAtt);
    // 4. out = x + attnout @ w_o^T + b_o  (N=1024: 128x64 tile, 512 blocks)
    gemm_n64<<<dim3(Dmod / 64, ROWS / 128), 256, 0, stream>>>(bufAtt, wo, b_o, x,
                                                              out, ROWS, Dmod, Dmod, Dmod, 0, 0);
    // 5. h2 = LN2(out)
    ln_kernel<<<ROWS, 256, 0, stream>>>(out, ln2_g, ln2_b, bufH);
    // 6. ff1 = gelu(h2 @ w_ff1^T + b_ff1)  FULL N=4096 (grid 32x32 = 1024 blocks)
    gemm_bt<<<dim3(HID / 128, ROWS / 128), 256, 0, stream>>>(bufH, wf1, b_ff1, nullptr,
                                                             bufFF, ROWS, HID, Dmod, Dmod, 1, 1);
    // 7. out = out + ff1 @ w_ff2^T + b_ff2  (N=1024, K=4096: 128x64 tile, 512 blocks)
    gemm_n64<<<dim3(Dmod / 64, ROWS / 128), 256, 0, stream>>>(bufFF, wf2, b_ff2, out,
                                                              out, ROWS, Dmod, HID, HID, 0, 0);
}

// Round 8
// 235.993 us; speedup vs baseline: 11.1415x; 1.0431x over previous
//
#include <hip/hip_runtime.h>
#include <hip/hip_bf16.h>
#include <cmath>

// Problem constants
#define Bsz 2
#define Lseq 2048
#define Dmod 1024
#define Hhead 16
#define DH 64
#define HID 4096
#define ROWS (Bsz * Lseq)   // 4096
#define TD (3 * Dmod)       // 3072

typedef __attribute__((ext_vector_type(8))) short bf16x8;
typedef __attribute__((ext_vector_type(4))) float f32x4;
typedef unsigned short ushort_t;

typedef const __attribute__((address_space(1))) void gv_t;
typedef __attribute__((address_space(3))) void lv_t;
#define GLDS16(GP, LP) __builtin_amdgcn_global_load_lds((gv_t*)(GP), (lv_t*)(LP), 16, 0, 0)

__device__ __forceinline__ float bf2f(short u)
{
    return __uint_as_float(((unsigned)(unsigned short)u) << 16);
}
__device__ __forceinline__ unsigned pack2(float a, float b)
{
    __hip_bfloat162 t;
    t.x = __float2bfloat16(a);
    t.y = __float2bfloat16(b);
    return *reinterpret_cast<unsigned*>(&t);
}
__device__ __forceinline__ float gelu_exact(float t)
{
    return 0.5f * t * (1.0f + erff(t * 0.70710678118654752f));
}

// Bijective XCD-aware block remap (T1, m-major within each XCD's chunk).
__device__ __forceinline__ void xcd_remap(int& mblk, int& nblk)
{
    int nx = gridDim.x;
    int nwg = nx * gridDim.y;
    int id = blockIdx.y * nx + blockIdx.x;
    int cpx = nwg >> 3;
    int swz = (id & 7) * cpx + (id >> 3);
    mblk = swz / nx;
    nblk = swz % nx;
}

// ---------------------------------------------------------------------------
// fp32 -> bf16 conversion of all 4 weight tensors in ONE dispatch.
// blocks: wq 3072 | wo 1024 | wf1 4096 | wf2 4096  (total 12288)
// ---------------------------------------------------------------------------
__global__ __launch_bounds__(256) void f2b4_kernel(const float* __restrict__ s0, ushort_t* __restrict__ d0,
                                                   const float* __restrict__ s1, ushort_t* __restrict__ d1,
                                                   const float* __restrict__ s2, ushort_t* __restrict__ d2,
                                                   const float* __restrict__ s3, ushort_t* __restrict__ d3)
{
    int blk = blockIdx.x;
    const float* src;
    ushort_t* dst;
    int base;
    if (blk < 3072)      { src = s0; dst = d0; base = blk; }
    else if (blk < 4096) { src = s1; dst = d1; base = blk - 3072; }
    else if (blk < 8192) { src = s2; dst = d2; base = blk - 4096; }
    else                 { src = s3; dst = d3; base = blk - 8192; }
    int i = base * 256 + threadIdx.x;
    float4 v = reinterpret_cast<const float4*>(src)[i];
    uint2 o;
    o.x = pack2(v.x, v.y);
    o.y = pack2(v.z, v.w);
    reinterpret_cast<uint2*>(dst)[i] = o;
}

// ---------------------------------------------------------------------------
// LayerNorm: one block per row of D=1024, float4 in, bf16 out.
// ---------------------------------------------------------------------------
__global__ __launch_bounds__(256) void ln_kernel(const float* __restrict__ x,
                                                 const float* __restrict__ g,
                                                 const float* __restrict__ bta,
                                                 ushort_t* __restrict__ out)
{
    int row = blockIdx.x;
    int t = threadIdx.x;
    const float4* xr = reinterpret_cast<const float4*>(x) + (size_t)row * 256;
    float4 v = xr[t];
    float s  = v.x + v.y + v.z + v.w;
    float s2 = v.x * v.x + v.y * v.y + v.z * v.z + v.w * v.w;
#pragma unroll
    for (int o = 32; o > 0; o >>= 1) {
        s  += __shfl_down(s, o);
        s2 += __shfl_down(s2, o);
    }
    __shared__ float sa[4], sb[4];
    int wv = t >> 6, ln = t & 63;
    if (ln == 0) { sa[wv] = s; sb[wv] = s2; }
    __syncthreads();
    s  = sa[0] + sa[1] + sa[2] + sa[3];
    s2 = sb[0] + sb[1] + sb[2] + sb[3];
    float mean = s * (1.0f / 1024.0f);
    float var  = s2 * (1.0f / 1024.0f) - mean * mean;
    float inv  = rsqrtf(var + 1e-5f);
    float4 gv = reinterpret_cast<const float4*>(g)[t];
    float4 bv = reinterpret_cast<const float4*>(bta)[t];
    uint2 o;
    o.x = pack2((v.x - mean) * inv * gv.x + bv.x, (v.y - mean) * inv * gv.y + bv.y);
    o.y = pack2((v.z - mean) * inv * gv.z + bv.z, (v.w - mean) * inv * gv.w + bv.w);
    reinterpret_cast<uint2*>(out)[(size_t)row * 256 + t] = o;
}

// ---------------------------------------------------------------------------
// bf16 MFMA GEMM (NT), 128x128 tile, BK=64, XOR chunk-swizzled LDS,
// COUNTED-VMCNT deep prefetch (T3+T4):
//   prologue: stage(t0); stage(t1)            (16 loads/wave in flight)
//   iter t  : s_waitcnt vmcnt(8)  <- tile t landed, tile t+1 still in flight
//             s_barrier            <- publish all waves' tile-t LDS writes
//             sched_barrier(0)     <- rule #18: keep ds_reads below barrier
//             compute(buf[t&1])
//             s_barrier            <- all waves done reading buf[t&1]
//             stage(buf[t&1], t+2)
//   tail    : vmcnt(8) / vmcnt(0) peeled iterations (no more stages).
// vmcnt is per-wave (8 loads/wave/tile); the barrier after every wave's
// vmcnt makes tile t globally visible. Never drains to 0 in steady state.
// ---------------------------------------------------------------------------
__global__ __launch_bounds__(256) void gemm_bt(const ushort_t* __restrict__ A,
                                               const ushort_t* __restrict__ W,
                                               const float* __restrict__ bias,
                                               const float* __restrict__ res,
                                               void* __restrict__ C,
                                               int M, int N, int K, int ldw,
                                               int act, int obf)
{
    __shared__ ushort_t As0[128 * 64];   // 16 KB each, 64 KB total
    __shared__ ushort_t Bs0[128 * 64];
    __shared__ ushort_t As1[128 * 64];
    __shared__ ushort_t Bs1[128 * 64];

    int tid = threadIdx.x;
    int w = tid >> 6, lane = tid & 63;
    int mblk, nblk;
    xcd_remap(mblk, nblk);
    int m0 = mblk * 128, n0 = nblk * 128;
    int wr = (w >> 1) * 64, wc = (w & 1) * 64;

    int srow = lane >> 3;
    int scol = (((lane & 7) ^ (lane >> 3)) & 7) * 8;   // pre-swizzled source chunk
    const ushort_t* ga[4];
    const ushort_t* gb[4];
    int lofs[4];
#pragma unroll
    for (int q = 0; q < 4; ++q) {
        ga[q] = A + (size_t)(m0 + w * 32 + q * 8 + srow) * K + scol;
        gb[q] = W + (size_t)(n0 + w * 32 + q * 8 + srow) * ldw + scol;
        lofs[q] = (w * 32 + q * 8) * 64;
    }

    int fr = lane & 15;
    int fg = lane >> 4;          // k-chunk group 0..3
    int r0 = fg * 4;
    int cc = fr;

    f32x4 acc[4][4] = {};

    auto stage = [&](ushort_t* AS, ushort_t* BS, int k0) {
#pragma unroll
        for (int q = 0; q < 4; ++q) {
            GLDS16(ga[q] + k0, AS + lofs[q]);
            GLDS16(gb[q] + k0, BS + lofs[q]);
        }
    };
    auto compute = [&](const ushort_t* AS, const ushort_t* BS) {
#pragma unroll
        for (int kk = 0; kk < 2; ++kk) {
            bf16x8 af[4], bfr[4];
            int ca = ((kk * 4 + fg) ^ (fr & 7)) * 8;   // swizzled chunk
#pragma unroll
            for (int i = 0; i < 4; ++i) {
                af[i]  = *reinterpret_cast<const bf16x8*>(&AS[(wr + i * 16 + fr) * 64 + ca]);
                bfr[i] = *reinterpret_cast<const bf16x8*>(&BS[(wc + i * 16 + fr) * 64 + ca]);
            }
#pragma unroll
            for (int mi = 0; mi < 4; ++mi)
#pragma unroll
                for (int ni = 0; ni < 4; ++ni)
                    acc[mi][ni] = __builtin_amdgcn_mfma_f32_16x16x32_bf16(
                        af[mi], bfr[ni], acc[mi][ni], 0, 0, 0);
        }
    };

    int nt = K >> 6;    // 16 or 64: even, >= 4
    stage(As0, Bs0, 0);
    stage(As1, Bs1, 64);
    int t = 0;
    for (; t + 3 < nt; t += 2) {
        asm volatile("s_waitcnt vmcnt(8)" ::: "memory");
        __builtin_amdgcn_s_barrier();
        __builtin_amdgcn_sched_barrier(0);
        compute(As0, Bs0);
        __builtin_amdgcn_s_barrier();
        stage(As0, Bs0, (t + 2) * 64);

        asm volatile("s_waitcnt vmcnt(8)" ::: "memory");
        __builtin_amdgcn_s_barrier();
        __builtin_amdgcn_sched_barrier(0);
        compute(As1, Bs1);
        __builtin_amdgcn_s_barrier();
        stage(As1, Bs1, (t + 3) * 64);
    }
    // tail: tiles nt-2 (buf0) and nt-1 (buf1) staged, nothing further issued
    asm volatile("s_waitcnt vmcnt(8)" ::: "memory");
    __builtin_amdgcn_s_barrier();
    __builtin_amdgcn_sched_barrier(0);
    compute(As0, Bs0);
    asm volatile("s_waitcnt vmcnt(0)" ::: "memory");
    __builtin_amdgcn_s_barrier();
    __builtin_amdgcn_sched_barrier(0);
    compute(As1, Bs1);

    float bv[4];
#pragma unroll
    for (int ni = 0; ni < 4; ++ni)
        bv[ni] = bias ? bias[n0 + wc + ni * 16 + cc] : 0.0f;

#pragma unroll
    for (int mi = 0; mi < 4; ++mi) {
#pragma unroll
        for (int r = 0; r < 4; ++r) {
            int row = m0 + wr + mi * 16 + r0 + r;
            const float* resrow = res ? res + (size_t)row * N : nullptr;
#pragma unroll
            for (int ni = 0; ni < 4; ++ni) {
                int col = n0 + wc + ni * 16 + cc;
                float v = acc[mi][ni][r] + bv[ni];
                if (act == 1) v = gelu_exact(v);
                if (resrow) v += resrow[col];
                if (obf) {
                    reinterpret_cast<ushort_t*>(C)[(size_t)row * N + col] =
                        (ushort_t)__bfloat16_as_ushort(__float2bfloat16(v));
                } else {
                    reinterpret_cast<float*>(C)[(size_t)row * N + col] = v;
                }
            }
        }
    }
}

// ---------------------------------------------------------------------------
// bf16 MFMA GEMM (NT), 128(M) x 64(N) tile, BK=64, swizzle + remap,
// same counted-vmcnt deep prefetch (6 loads/wave/tile -> vmcnt(6)).
// ---------------------------------------------------------------------------
__global__ __launch_bounds__(256) void gemm_n64(const ushort_t* __restrict__ A,
                                                const ushort_t* __restrict__ W,
                                                const float* __restrict__ bias,
                                                const float* __restrict__ res,
                                                void* __restrict__ C,
                                                int M, int N, int K, int ldw,
                                                int act, int obf)
{
    __shared__ ushort_t As0[128 * 64];   // 16 KB
    __shared__ ushort_t Bs0[64 * 64];    //  8 KB
    __shared__ ushort_t As1[128 * 64];
    __shared__ ushort_t Bs1[64 * 64];

    int tid = threadIdx.x;
    int w = tid >> 6, lane = tid & 63;
    int mblk, nblk;
    xcd_remap(mblk, nblk);
    int m0 = mblk * 128, n0 = nblk * 64;
    int wr = (w >> 1) * 64, wc = (w & 1) * 32;

    int srow = lane >> 3;
    int scol = (((lane & 7) ^ (lane >> 3)) & 7) * 8;
    const ushort_t* ga[4];
    const ushort_t* gb[2];
    int laofs[4], lbofs[2];
#pragma unroll
    for (int q = 0; q < 4; ++q) {
        ga[q] = A + (size_t)(m0 + w * 32 + q * 8 + srow) * K + scol;
        laofs[q] = (w * 32 + q * 8) * 64;
    }
#pragma unroll
    for (int q = 0; q < 2; ++q) {
        gb[q] = W + (size_t)(n0 + w * 16 + q * 8 + srow) * ldw + scol;
        lbofs[q] = (w * 16 + q * 8) * 64;
    }

    int fr = lane & 15;
    int fg = lane >> 4;
    int r0 = fg * 4;
    int cc = fr;

    f32x4 acc[4][2] = {};

    auto stage = [&](ushort_t* AS, ushort_t* BS, int k0) {
#pragma unroll
        for (int q = 0; q < 4; ++q) GLDS16(ga[q] + k0, AS + laofs[q]);
#pragma unroll
        for (int q = 0; q < 2; ++q) GLDS16(gb[q] + k0, BS + lbofs[q]);
    };
    auto compute = [&](const ushort_t* AS, const ushort_t* BS) {
#pragma unroll
        for (int kk = 0; kk < 2; ++kk) {
            bf16x8 af[4], bfr[2];
            int ca = ((kk * 4 + fg) ^ (fr & 7)) * 8;
#pragma unroll
            for (int i = 0; i < 4; ++i)
                af[i] = *reinterpret_cast<const bf16x8*>(&AS[(wr + i * 16 + fr) * 64 + ca]);
#pragma unroll
            for (int i = 0; i < 2; ++i)
                bfr[i] = *reinterpret_cast<const bf16x8*>(&BS[(wc + i * 16 + fr) * 64 + ca]);
#pragma unroll
            for (int mi = 0; mi < 4; ++mi)
#pragma unroll
                for (int ni = 0; ni < 2; ++ni)
                    acc[mi][ni] = __builtin_amdgcn_mfma_f32_16x16x32_bf16(
                        af[mi], bfr[ni], acc[mi][ni], 0, 0, 0);
        }
    };

    int nt = K >> 6;    // 16 or 64
    stage(As0, Bs0, 0);
    stage(As1, Bs1, 64);
    int t = 0;
    for (; t + 3 < nt; t += 2) {
        asm volatile("s_waitcnt vmcnt(6)" ::: "memory");
        __builtin_amdgcn_s_barrier();
        __builtin_amdgcn_sched_barrier(0);
        compute(As0, Bs0);
        __builtin_amdgcn_s_barrier();
        stage(As0, Bs0, (t + 2) * 64);

        asm volatile("s_waitcnt vmcnt(6)" ::: "memory");
        __builtin_amdgcn_s_barrier();
        __builtin_amdgcn_sched_barrier(0);
        compute(As1, Bs1);
        __builtin_amdgcn_s_barrier();
        stage(As1, Bs1, (t + 3) * 64);
    }
    asm volatile("s_waitcnt vmcnt(6)" ::: "memory");
    __builtin_amdgcn_s_barrier();
    __builtin_amdgcn_sched_barrier(0);
    compute(As0, Bs0);
    asm volatile("s_waitcnt vmcnt(0)" ::: "memory");
    __builtin_amdgcn_s_barrier();
    __builtin_amdgcn_sched_barrier(0);
    compute(As1, Bs1);

    float bv[2];
#pragma unroll
    for (int ni = 0; ni < 2; ++ni)
        bv[ni] = bias ? bias[n0 + wc + ni * 16 + cc] : 0.0f;

#pragma unroll
    for (int mi = 0; mi < 4; ++mi) {
#pragma unroll
        for (int r = 0; r < 4; ++r) {
            int row = m0 + wr + mi * 16 + r0 + r;
            const float* resrow = res ? res + (size_t)row * N : nullptr;
#pragma unroll
            for (int ni = 0; ni < 2; ++ni) {
                int col = n0 + wc + ni * 16 + cc;
                float v = acc[mi][ni][r] + bv[ni];
                if (act == 1) v = gelu_exact(v);
                if (resrow) v += resrow[col];
                if (obf) {
                    reinterpret_cast<ushort_t*>(C)[(size_t)row * N + col] =
                        (ushort_t)__bfloat16_as_ushort(__float2bfloat16(v));
                } else {
                    reinterpret_cast<float*>(C)[(size_t)row * N + col] = v;
                }
            }
        }
    }
}

// ---------------------------------------------------------------------------
// Flash-style dilated attention via parity compression (unchanged, verified).
// ---------------------------------------------------------------------------
__global__ __launch_bounds__(256) void attn_mfma(const ushort_t* __restrict__ qkv,
                                                 ushort_t* __restrict__ out)
{
    __shared__ ushort_t Vt[64][328];
    __shared__ ushort_t Pw[4][16][40];

    int bid = blockIdx.x;
    int qt = bid & 15, h = (bid >> 4) & 15, p = (bid >> 8) & 1, b = bid >> 9;
    int qt0 = qt * 64;
    int kstart = qt0 - 256;

    const ushort_t* base = qkv + (size_t)b * Lseq * TD;
    int tid = threadIdx.x;

#pragma unroll
    for (int it = 0; it < 10; ++it) {
        int idx = it * 256 + tid;
        int ko = idx >> 3;
        int dg = idx & 7;
        int kk = kstart + ko;
        bf16x8 v = {};
        if (kk >= 0)
            v = *reinterpret_cast<const bf16x8*>(base + (size_t)(2 * kk + p) * TD + 2048 + h * 64 + dg * 8);
#pragma unroll
        for (int j = 0; j < 8; ++j)
            Vt[dg * 8 + j][ko] = (ushort_t)v[j];
    }

    int w = tid >> 6, lane = tid & 63;
    int fr = lane & 15, fg = lane >> 4;
    int qw = qt0 + w * 16;
    const ushort_t* qrow = base + (size_t)(2 * (qw + fr) + p) * TD + h * 64;
    bf16x8 qf0 = *reinterpret_cast<const bf16x8*>(qrow + fg * 8);
    bf16x8 qf1 = *reinterpret_cast<const bf16x8*>(qrow + 32 + fg * 8);

    __syncthreads();

    float m[4]    = {-1e30f, -1e30f, -1e30f, -1e30f};
    float lsum[4] = {};
    f32x4 o[4]    = {};
    const float scale = 0.125f;
    int qbase = qw + fg * 4;

    for (int t = 0; t < 10; ++t) {
        int kt0 = kstart + t * 32;
        int kk0 = kt0 + fr, kk1 = kk0 + 16;
        int kk0c = kk0 < 0 ? 0 : kk0;
        int kk1c = kk1 < 0 ? 0 : kk1;
        const ushort_t* kr0 = base + (size_t)(2 * kk0c + p) * TD + 1024 + h * 64;
        const ushort_t* kr1 = base + (size_t)(2 * kk1c + p) * TD + 1024 + h * 64;
        bf16x8 k00 = *reinterpret_cast<const bf16x8*>(kr0 + fg * 8);
        bf16x8 k01 = *reinterpret_cast<const bf16x8*>(kr0 + 32 + fg * 8);
        bf16x8 k10 = *reinterpret_cast<const bf16x8*>(kr1 + fg * 8);
        bf16x8 k11 = *reinterpret_cast<const bf16x8*>(kr1 + 32 + fg * 8);

        f32x4 s0 = {}, s1 = {};
        s0 = __builtin_amdgcn_mfma_f32_16x16x32_bf16(qf0, k00, s0, 0, 0, 0);
        s0 = __builtin_amdgcn_mfma_f32_16x16x32_bf16(qf1, k01, s0, 0, 0, 0);
        s1 = __builtin_amdgcn_mfma_f32_16x16x32_bf16(qf0, k10, s1, 0, 0, 0);
        s1 = __builtin_amdgcn_mfma_f32_16x16x32_bf16(qf1, k11, s1, 0, 0, 0);

        int c0 = kt0 + fr, c1 = c0 + 16;
        float v0[4], v1[4], tmax[4];
#pragma unroll
        for (int r = 0; r < 4; ++r) {
            int qq = qbase + r;
            bool a0 = (c0 >= 0) && (c0 <= qq) && (c0 >= qq - 256);
            bool a1 = (c1 >= 0) && (c1 <= qq) && (c1 >= qq - 256);
            v0[r] = a0 ? s0[r] * scale : -1e30f;
            v1[r] = a1 ? s1[r] * scale : -1e30f;
            tmax[r] = fmaxf(v0[r], v1[r]);
        }
#pragma unroll
        for (int off = 1; off < 16; off <<= 1) {
#pragma unroll
            for (int r = 0; r < 4; ++r)
                tmax[r] = fmaxf(tmax[r], __shfl_xor(tmax[r], off));
        }
#pragma unroll
        for (int r = 0; r < 4; ++r) {
            float mn = fmaxf(m[r], tmax[r]);
            float corr = __expf(m[r] - mn);
            m[r] = mn;
            float p0 = __expf(v0[r] - mn);
            float p1 = __expf(v1[r] - mn);
            lsum[r] = lsum[r] * corr + p0 + p1;
#pragma unroll
            for (int db = 0; db < 4; ++db)
                o[db][r] *= corr;
            Pw[w][fg * 4 + r][fr]      = (ushort_t)__bfloat16_as_ushort(__float2bfloat16(p0));
            Pw[w][fg * 4 + r][fr + 16] = (ushort_t)__bfloat16_as_ushort(__float2bfloat16(p1));
        }

        bf16x8 pf = *reinterpret_cast<const bf16x8*>(&Pw[w][fr][fg * 8]);
#pragma unroll
        for (int db = 0; db < 4; ++db) {
            bf16x8 vf = *reinterpret_cast<const bf16x8*>(&Vt[db * 16 + fr][t * 32 + fg * 8]);
            o[db] = __builtin_amdgcn_mfma_f32_16x16x32_bf16(pf, vf, o[db], 0, 0, 0);
        }
    }

#pragma unroll
    for (int off = 1; off < 16; off <<= 1) {
#pragma unroll
        for (int r = 0; r < 4; ++r)
            lsum[r] += __shfl_xor(lsum[r], off);
    }
    float inv[4];
#pragma unroll
    for (int r = 0; r < 4; ++r) inv[r] = 1.0f / lsum[r];

#pragma unroll
    for (int r = 0; r < 4; ++r) {
        size_t orow = ((size_t)b * Lseq + 2 * (qbase + r) + p) * Dmod + h * 64;
#pragma unroll
        for (int db = 0; db < 4; ++db)
            out[orow + db * 16 + fr] =
                (ushort_t)__bfloat16_as_ushort(__float2bfloat16(o[db][r] * inv[r]));
    }
}

// ---------------------------------------------------------------------------
// Launch.  Workspace (bf16 elems), total 33.554M = 67.1 MB:
//   wq 3.146M | wo 1.049M | wf1 4.194M | wf2 4.194M   (bf16 weights)
//   bufFF 16.777M : qkv (12.58M) -> ff1 FULL [4096][4096]  (qkv dead by then)
//   bufH   2.097M : h -> h2
//   bufAtt 2.097M : attnout
// ---------------------------------------------------------------------------
extern "C" void kernel_launch(void* const* d_in, const int* in_sizes, int n_in,
                              void* d_out, int out_size, void* d_ws, size_t ws_size,
                              hipStream_t stream)
{
    const float* x     = (const float*)d_in[0];
    const float* ln1_g = (const float*)d_in[1];
    const float* ln1_b = (const float*)d_in[2];
    const float* w_qkv = (const float*)d_in[3];
    const float* b_qkv = (const float*)d_in[4];
    const float* w_o   = (const float*)d_in[5];
    const float* b_o   = (const float*)d_in[6];
    const float* ln2_g = (const float*)d_in[7];
    const float* ln2_b = (const float*)d_in[8];
    const float* w_ff1 = (const float*)d_in[9];
    const float* b_ff1 = (const float*)d_in[10];
    const float* w_ff2 = (const float*)d_in[11];
    const float* b_ff2 = (const float*)d_in[12];
    float* out = (float*)d_out;

    ushort_t* wq     = (ushort_t*)d_ws;
    ushort_t* wo     = wq  + (size_t)TD * Dmod;
    ushort_t* wf1    = wo  + (size_t)Dmod * Dmod;
    ushort_t* wf2    = wf1 + (size_t)HID * Dmod;
    ushort_t* bufFF  = wf2 + (size_t)Dmod * HID;
    ushort_t* bufH   = bufFF + (size_t)ROWS * HID;
    ushort_t* bufAtt = bufH + (size_t)ROWS * Dmod;

    f2b4_kernel<<<12288, 256, 0, stream>>>(w_qkv, wq, w_o, wo, w_ff1, wf1, w_ff2, wf2);

    // 1. h = LN1(x)
    ln_kernel<<<ROWS, 256, 0, stream>>>(x, ln1_g, ln1_b, bufH);
    // 2. qkv = h @ w_qkv^T + b_qkv  (768 blocks)
    gemm_bt<<<dim3(TD / 128, ROWS / 128), 256, 0, stream>>>(bufH, wq, b_qkv, nullptr,
                                                            bufFF, ROWS, TD, Dmod, Dmod, 0, 1);
    // 3. attnout = flash dilated attention
    attn_mfma<<<Bsz * 2 * Hhead * (1024 / 64), 256, 0, stream>>>(bufFF, bufAtt);
    // 4. out = x + attnout @ w_o^T + b_o  (512 blocks)
    gemm_n64<<<dim3(Dmod / 64, ROWS / 128), 256, 0, stream>>>(bufAtt, wo, b_o, x,
                                                              out, ROWS, Dmod, Dmod, Dmod, 0, 0);
    // 5. h2 = LN2(out)
    ln_kernel<<<ROWS, 256, 0, stream>>>(out, ln2_g, ln2_b, bufH);
    // 6. ff1 = gelu(h2 @ w_ff1^T + b_ff1)  (1024 blocks)
    gemm_bt<<<dim3(HID / 128, ROWS / 128), 256, 0, stream>>>(bufH, wf1, b_ff1, nullptr,
                                                             bufFF, ROWS, HID, Dmod, Dmod, 1, 1);
    // 7. out = out + ff1 @ w_ff2^T + b_ff2  (512 blocks, K=4096)
    gemm_n64<<<dim3(Dmod / 64, ROWS / 128), 256, 0, stream>>>(bufFF, wf2, b_ff2, out,
                                                              out, ROWS, Dmod, HID, HID, 0, 0);
}